// Round 1
// baseline (357.339 us; speedup 1.0000x reference)
//
#include <hip/hip_runtime.h>
#include <stdint.h>

// No implicit FMA contraction: the JAX eager reference has none across ops;
// where XLA fuses we write fmaf() explicitly.
#pragma clang fp contract(off)

#define PDIM 162
#define NW   (2*PDIM*PDIM*3)   // 157464 words, 1.26 MB per bitboard
#define NWH  (NW/2)            // 78732
#define OD   160

// R12 occupancy restructure: core 16(z) x 8(y), halo 8 -> 32x24 LDS tile,
// 512 threads, grid 2x10x20 = 400 blocks. LDS 2x18.7KB = 37.4KB/block ->
// 4 blocks/CU by both LDS (4x37.4=149.5KB<160KB) and threads (4x512=2048).
// Whole grid co-resident; inter-block overlap hides barrier/LDS latency
// that left VALUBusy at 17% with the old 200x1024 shape.
#define TZ 32                  // tile z rows (16 core + 2*8 halo)
#define TY 24                  // tile y rows ( 8 core + 2*8 halo)
#define CZ 16
#define CY 8
#define PZ 73                  // u64 per z-row (>= TY*3 = 72)
#define LADDR(lz,ly) ((lz)*PZ + (ly)*3)

// ---------------- threefry2x32, JAX partitionable scheme --------------------
__device__ __forceinline__ uint32_t rotl32(uint32_t x, uint32_t r) {
  return (x << r) | (x >> (32u - r));
}

__device__ __forceinline__ uint32_t threefry_bits(uint32_t idx) {
  const uint32_t ks0 = 0u, ks1 = 42u, ks2 = 0x1BD11BDAu ^ 0u ^ 42u;
  uint32_t x0 = 0u + ks0;
  uint32_t x1 = idx + ks1;
#define TFR(r) { x0 += x1; x1 = rotl32(x1, (r)); x1 ^= x0; }
  TFR(13u) TFR(15u) TFR(26u) TFR(6u)
  x0 += ks1; x1 += ks2 + 1u;
  TFR(17u) TFR(29u) TFR(16u) TFR(24u)
  x0 += ks2; x1 += ks0 + 2u;
  TFR(13u) TFR(15u) TFR(26u) TFR(6u)
  x0 += ks0; x1 += ks1 + 3u;
  TFR(17u) TFR(29u) TFR(16u) TFR(24u)
  x0 += ks1; x1 += ks2 + 4u;
  TFR(13u) TFR(15u) TFR(26u) TFR(6u)
  x0 += ks2; x1 += ks0 + 5u;
#undef TFR
  return x0 ^ x1;
}

// ------------- XLA-CPU (Cephes) float32 log replication ---------------------
__device__ __forceinline__ float xla_logf(float xin) {
  uint32_t bits = __float_as_uint(xin);
  float e = (float)((int)(bits >> 23) - 126);
  float x = __uint_as_float((bits & 0x007fffffu) | 0x3f000000u);
  const float SQRTHF = 0.707106781186547524f;
  bool lt = (x < SQRTHF);
  float tmp = lt ? x : 0.0f;
  e = e - (lt ? 1.0f : 0.0f);
  x = x - 1.0f;
  x = x + tmp;
  float z = x * x;
  float y = 7.0376836292e-2f;
  y = fmaf(y, x, -1.1514610310e-1f);
  y = fmaf(y, x,  1.1676998740e-1f);
  y = fmaf(y, x, -1.2420140846e-1f);
  y = fmaf(y, x,  1.4249322787e-1f);
  y = fmaf(y, x, -1.6668057665e-1f);
  y = fmaf(y, x,  2.0000714765e-1f);
  y = fmaf(y, x, -2.4999993993e-1f);
  y = fmaf(y, x,  3.3333331174e-1f);
  y = y * x;
  y = y * z;
  y = fmaf(e, -2.12194440e-4f, y);
  y = fmaf(-0.5f, z, y);
  x = x + y;
  x = fmaf(e, 0.693359375f, x);
  return x;
}

__device__ __forceinline__ float xla_log1pf(float x) {
  float for_large = xla_logf(x + 1.0f);
  float for_small = fmaf(-0.5f, x, 1.0f) * x;
  return (fabsf(x) < 1e-4f) ? for_small : for_large;
}

// one voxel's decision (exact JAX/XLA bit replication)
__device__ __forceinline__ bool bin_pred(const float* __restrict__ in, uint32_t w,
                                         uint32_t lane) {
  uint32_t row = w / 3u, wx = w - row * 3u;
  uint32_t n  = row / (uint32_t)(PDIM * PDIM);
  uint32_t rr = row - n * (uint32_t)(PDIM * PDIM);
  uint32_t z  = rr / (uint32_t)PDIM;
  uint32_t y  = rr - z * (uint32_t)PDIM;
  uint32_t x  = wx * 64u + lane;
  // pad voxels are provably 0: |0.33*noise| <= 6.08 < 18.42 = |log alpha(0)|
  if ((z - 1u) >= 160u || (y - 1u) >= 160u || (x - 1u) >= 160u) return false;
  float v = in[((n * 160u + (z - 1u)) * 160u + (y - 1u)) * 160u + (x - 1u)];
  uint32_t i = row * 162u + x;            // flat padded index for RNG
  uint32_t b = threefry_bits(i);
  float f  = __uint_as_float((b >> 9) | 0x3f800000u) - 1.0f;
  float uu = fmaxf(1e-8f, f + 1e-8f);
  float la = xla_logf((v + 1e-8f) / ((1.0f - v) + 1e-8f));
  float noise = xla_logf(uu) - xla_log1pf(-uu);
  float zs = la + noise * 0.33f;
  return (zs > 1.1920928955078125e-7f);   // logistic>0.5 iff z>2^-23
}

// ---------------------------- binarize --------------------------------------
// ILP-2: each wave produces TWO words (w and w+NW/2).
__global__ __launch_bounds__(256) void k_binarize(const float* __restrict__ in,
                                                  uint64_t* __restrict__ bits) {
  uint32_t t = blockIdx.x * 256u + threadIdx.x;
  uint32_t w0 = t >> 6, lane = t & 63u;
  if (w0 >= (uint32_t)NWH) return;        // wave-uniform
  uint32_t w1 = w0 + (uint32_t)NWH;
  bool p0 = bin_pred(in, w0, lane);
  bool p1 = bin_pred(in, w1, lane);
  uint64_t m0 = __ballot(p0);
  uint64_t m1 = __ballot(p1);
  if (lane == 0) { bits[w0] = m0; bits[w1] = m1; }
}

// ------------- per-word neighborhood from LDS row triples -------------------
#define NB(dz,dy,dx) ((dx)==-1 ? Lb[(dz)+1][(dy)+1] : ((dx)==1 ? Rb[(dz)+1][(dy)+1] : Vv[(dz)+1][(dy)+1]))

#define GATHER_W(SRC, lz, ly, w) \
  _Pragma("unroll") \
  for (int dz = 0; dz < 3; ++dz) \
    _Pragma("unroll") \
    for (int dy = 0; dy < 3; ++dy) { \
      int rb = LADDR((lz) + dz - 1, (ly) + dy - 1); \
      uint64_t r0 = SRC[rb], r1 = SRC[rb + 1], r2 = SRC[rb + 2]; \
      uint64_t b = ((w) == 0) ? r0 : (((w) == 1) ? r1 : r2); \
      uint64_t a = ((w) == 0) ? 0ull : (((w) == 1) ? r0 : r1); \
      uint64_t d = ((w) == 0) ? r1 : (((w) == 1) ? r2 : 0ull); \
      Vv[dz][dy] = b; \
      Lb[dz][dy] = (b << 1) | (a >> 63); \
      Rb[dz][dy] = (b >> 1) | (d << 63); \
    }

// ---- balanced (OR, GE2) reduction: low serial depth for latency hiding ----
struct OG { uint64_t o, g; };
__device__ __forceinline__ OG og_leaf2(uint64_t a, uint64_t b) {
  OG r; r.o = a | b; r.g = a & b; return r;
}
__device__ __forceinline__ OG og_comb(OG a, OG b) {
  OG r; r.g = a.g | b.g | (a.o & b.o); r.o = a.o | b.o; return r;
}

// OG over the 18-neighborhood (faces+edges) and corners; both trees depth ~4.
#define OG_BUILD_18_C(og18, ogc) \
  OG a0 = og_leaf2(NB(-1,0,0), NB(1,0,0)); \
  OG a1 = og_leaf2(NB(0,-1,0), NB(0,1,0)); \
  OG a2 = og_leaf2(NB(0,0,-1), NB(0,0,1)); \
  OG e0 = og_leaf2(NB(-1,-1,0), NB(-1,1,0)); \
  OG e1 = og_leaf2(NB(-1,0,-1), NB(-1,0,1)); \
  OG e2 = og_leaf2(NB(1,-1,0),  NB(1,1,0)); \
  OG e3 = og_leaf2(NB(1,0,-1),  NB(1,0,1)); \
  OG e4 = og_leaf2(NB(0,-1,-1), NB(0,-1,1)); \
  OG e5 = og_leaf2(NB(0,1,-1),  NB(0,1,1)); \
  OG t0 = og_comb(a0, a1); \
  OG t1 = og_comb(a2, e0); \
  OG t2 = og_comb(e1, e2); \
  OG t3 = og_comb(e3, e4); \
  OG og18 = og_comb(og_comb(og_comb(t0, t1), og_comb(t2, t3)), e5); \
  OG c0 = og_leaf2(NB(-1,-1,-1), NB(-1,-1,1)); \
  OG c1 = og_leaf2(NB(-1,1,-1),  NB(-1,1,1)); \
  OG c2 = og_leaf2(NB(1,-1,-1),  NB(1,-1,1)); \
  OG c3 = og_leaf2(NB(1,1,-1),   NB(1,1,1)); \
  OG ogc = og_comb(og_comb(c0, c1), og_comb(c2, c3));

// ---------------------------- iteration kernel ------------------------------
// One block: 16x8 (z,y) core x full 192-bit x, halo 8 -> 32x24 LDS tile.
// ge2 on halo 7, then 8 subfield passes with shrinking halo; writes core only
// (or, final iteration, the float output directly from LDS).
__global__ __launch_bounds__(512, 8) void k_iter(const uint64_t* __restrict__ bin,
                                                 uint64_t* __restrict__ bout,
                                                 float4* __restrict__ outf,
                                                 int zero_pads) {
  __shared__ uint64_t Bt[TZ * PZ];
  __shared__ uint64_t Ge[TZ * PZ];
  const int tid = threadIdx.x;
  const int bid = blockIdx.x;
  const int n  = bid / 200;
  const int rm = bid - n * 200;
  const int tz = rm / 20, ty = rm - tz * 20;
  const int gz0 = 1 + 16 * tz, gy0 = 1 + 8 * ty;   // both odd

  // Zero bout's pad rows (z or y in {0,161}) once per replay (block 0, iter 1).
  if (zero_pads && bid == 0) {
    for (int j = tid; j < 1288; j += 512) {
      int nn, z, y;
      if (j < 648) { nn = j / 324; int r = j - nn * 324;
                     z = (r >= 162) ? 161 : 0; y = (r >= 162) ? r - 162 : r; }
      else { int j2 = j - 648; nn = j2 / 320; int r = j2 - nn * 320;
             y = (r >= 160) ? 161 : 0; z = 1 + ((r >= 160) ? r - 160 : r); }
      uint64_t* p = bout + (((nn * 162 + z) * 162) + y) * 3;
      p[0] = 0; p[1] = 0; p[2] = 0;
    }
  }

  // ---- load tile + halo 8 (w,ly fastest -> coalesced global reads) ----
  for (int ti = tid; ti < TZ * TY * 3; ti += 512) {
    int w = ti % 3, r = ti / 3, ly = r % TY, lz = r / TY;
    int z = gz0 - 8 + lz, y = gy0 - 8 + ly;
    uint64_t v = 0;
    if ((unsigned)z < 162u && (unsigned)y < 162u)
      v = bin[((n * 162 + z) * 162 + y) * 3 + w];
    Bt[LADDR(lz, ly) + w] = v;
  }
  __syncthreads();

  // ---- ge2 (C26>=2, not-endpoint) on halo 7 (30x22), tree reduction ----
  for (int ti = tid; ti < 30 * 22 * 3; ti += 512) {
    int w = ti % 3, r = ti / 3, iy = r % 22, iz = r / 22;
    int lz = 1 + iz, ly = 1 + iy;
    int base = LADDR(lz, ly) + w;
    uint64_t res = 0;
    if (Bt[base] != 0ull) {               // ge2 only consumed ANDed with center
      uint64_t Vv[3][3], Lb[3][3], Rb[3][3];
      GATHER_W(Bt, lz, ly, w)
      OG_BUILD_18_C(og18, ogc)
      res = og_comb(og18, ogc).g;         // GE2 over all 26
    }
    Ge[base] = res;
  }
  __syncthreads();

  // ---- 8 subfield passes, halo 7-k, parity per reference offsets order ----
  const int PLZ[8] = {1,0,1,0,1,0,1,0};   // lz parity (xo=0 -> z even -> lz odd)
  const int PLY[8] = {1,1,0,0,1,1,0,0};   // ly parity
#pragma unroll
  for (int k = 0; k < 8; ++k) {
    const int h = 7 - k;
    const int cntz = 8 + h, cnty = 4 + h;
    const uint64_t xmask = (k < 4) ? 0x5555555555555555ull : 0xAAAAAAAAAAAAAAAAull;
    const int s0 = 8 - h;
    const int slz = s0 + ((s0 ^ PLZ[k]) & 1);
    const int sly = s0 + ((s0 ^ PLY[k]) & 1);
    for (int ti = tid; ti < cntz * cnty * 3; ti += 512) {
      int w = ti % 3, r = ti / 3, iy = r % cnty, iz = r / cnty;
      int lz = slz + 2 * iz, ly = sly + 2 * iy;
      int base = LADDR(lz, ly) + w;
      uint64_t center = Bt[base];
      uint64_t act = center & xmask & Ge[base];
      if (act == 0ull) continue;
      uint64_t Vv[3][3], Lb[3][3], Rb[3][3];
      GATHER_W(Bt, lz, ly, w)

      // tree (OR,GE2) over 18-set and corners
      OG_BUILD_18_C(og18, ogc)
      OG og26 = og_comb(og18, ogc);
      uint64_t e18 = og18.o & ~og18.g;    // C18 == 1
      uint64_t e26 = og26.o & ~og26.g;    // C26 == 1

      // C6 via complemented faces: eq5 = exactly-1 missing, le4 = >=2 missing
      uint64_t m0f = ~NB(-1,0,0), m1f = ~NB(1,0,0), m2f = ~NB(0,-1,0);
      uint64_t m3f = ~NB(0,1,0),  m4f = ~NB(0,0,-1), m5f = ~NB(0,0,1);
      OG p0 = og_leaf2(m0f, m1f);
      OG p1 = og_leaf2(m2f, m3f);
      OG p2 = og_leaf2(m4f, m5f);
      OG pm = og_comb(og_comb(p0, p1), p2);
      uint64_t c6eq5 = pm.o & ~pm.g;
      uint64_t c6le4 = pm.g;

      uint64_t del = (c6eq5 | e26) & act;
      // B/A patterns only where a candidate isn't already decided
      uint64_t need = act & ~del & (e18 | c6le4);
      if (need != 0ull) {
        // B: corner set with its 6 octant face/edge cells all clear
        uint64_t badB = 0;
#pragma unroll
        for (int sz = -1; sz <= 1; sz += 2)
#pragma unroll
          for (int sy = -1; sy <= 1; sy += 2)
#pragma unroll
            for (int sx = -1; sx <= 1; sx += 2) {
              uint64_t oct = NB(sz,0,0) | NB(0,sy,0) | NB(0,0,sx)
                           | NB(sz,sy,0) | NB(sz,0,sx) | NB(0,sy,sx);
              badB |= NB(sz,sy,sx) & ~oct;
            }
        uint64_t b0ok = ~badB;

        // A: face clear with its full 4-cell in-plane ring set
        uint64_t badA = 0;
        badA |= ~NB(-1,0,0) & NB(-1,-1,0) & NB(-1,1,0) & NB(-1,0,-1) & NB(-1,0,1);
        badA |= ~NB( 1,0,0) & NB( 1,-1,0) & NB( 1,1,0) & NB( 1,0,-1) & NB( 1,0,1);
        badA |= ~NB(0,-1,0) & NB(-1,-1,0) & NB(1,-1,0) & NB(0,-1,-1) & NB(0,-1,1);
        badA |= ~NB(0, 1,0) & NB(-1, 1,0) & NB(1, 1,0) & NB(0, 1,-1) & NB(0, 1,1);
        badA |= ~NB(0,0,-1) & NB(-1,0,-1) & NB(1,0,-1) & NB(0,-1,-1) & NB(0,1,-1);
        badA |= ~NB(0,0, 1) & NB(-1,0, 1) & NB(1,0, 1) & NB(0,-1, 1) & NB(0,1, 1);
        uint64_t a0ok = ~badA;

        del |= ((e18 & b0ok) | (c6le4 & a0ok & b0ok)) & act;
      }
      if (del) Bt[base] = center & ~del;
      // readers only consume non-updated-parity bits; tearing-safe (R5 arg)
    }
    __syncthreads();
  }

  // ---- epilogue ----
  if (outf) {
    // final iteration: write float output for core directly from LDS
    for (int ti = tid; ti < CZ * CY * 40; ti += 512) {
      int g = ti % 40, r = ti / 40, iy = r % CY, iz = r / CY;
      int base = LADDR(8 + iz, 8 + iy);
      int bi = 1 + 4 * g;                 // padded x of first of 4 floats
      int wx = bi >> 6, sft = bi & 63;
      uint64_t v = Bt[base + wx] >> sft;
      if (sft > 60) v |= Bt[base + wx + 1] << (64 - sft);
      outf[((n * 160 + (gz0 + iz - 1)) * 160 + (gy0 + iy - 1)) * 40 + g] =
          make_float4((float)(v & 1u), (float)((v >> 1) & 1u),
                      (float)((v >> 2) & 1u), (float)((v >> 3) & 1u));
    }
  } else {
    // write core words back (disjoint across blocks)
    for (int ti = tid; ti < CZ * CY * 3; ti += 512) {
      int w = ti % 3, r = ti / 3, iy = r % CY, iz = r / CY;
      bout[((n * 162 + gz0 + iz) * 162 + (gy0 + iy)) * 3 + w] =
          Bt[LADDR(8 + iz, 8 + iy) + w];
    }
  }
}

// ---------------------------- launcher --------------------------------------
extern "C" void kernel_launch(void* const* d_in, const int* in_sizes, int n_in,
                              void* d_out, int out_size, void* d_ws, size_t ws_size,
                              hipStream_t stream) {
  const float* in = (const float*)d_in[0];
  float4* out = (float4*)d_out;
  uint64_t* A = (uint64_t*)d_ws;          // bitboard A
  uint64_t* B = A + NW;                   // bitboard B

  k_binarize<<<dim3((NWH * 64 + 255) / 256), dim3(256), 0, stream>>>(in, A);
  k_iter<<<dim3(400), dim3(512), 0, stream>>>(A, B, nullptr, 1); // iter 1
  k_iter<<<dim3(400), dim3(512), 0, stream>>>(B, A, nullptr, 0); // iter 2
  k_iter<<<dim3(400), dim3(512), 0, stream>>>(A, B, nullptr, 0); // iter 3
  k_iter<<<dim3(400), dim3(512), 0, stream>>>(B, A, nullptr, 0); // iter 4
  k_iter<<<dim3(400), dim3(512), 0, stream>>>(A, nullptr, out, 0); // iter 5 -> out
}

// Round 2
// 304.100 us; speedup vs baseline: 1.1751x; 1.1751x over previous
//
#include <hip/hip_runtime.h>
#include <stdint.h>

// No implicit FMA contraction: the JAX eager reference has none across ops;
// where XLA fuses we write fmaf() explicitly.
#pragma clang fp contract(off)

#define PDIM 162
#define NW   (2*PDIM*PDIM*3)   // 157464 words, 1.26 MB per bitboard
#define NWH  (NW/2)            // 78732
#define OD   160

// R13: 8x8 core, halo 8 -> 24x24 LDS tile, 256 threads, grid 2x20x20 = 800.
// LDS 2x14.0KB = 28KB -> 5 blocks/CU by LDS, 8 by threads; grid gives ~3/CU.
// Multiple INDEPENDENT blocks per CU desynchronize the 10 barrier phases so
// one block's __syncthreads no longer idles the whole CU (R0: 1 block/CU,
// VALUBusy 17%). NO min-occupancy launch bound: R1's (512,8) forced VGPR=32
// and spilled the 27-word gather to scratch (WRITE_SIZE 1.3->45MB, k_iter
// real 38->59us). Redundant halo work ~1.8x R0 -- cheap at 17% VALUBusy.
#define NTHREADS 256
#define TZ 24                  // tile z rows ( 8 core + 2*8 halo)
#define TY 24                  // tile y rows ( 8 core + 2*8 halo)
#define CZ 8
#define CY 8
#define PZ 73                  // u64 per z-row (>= TY*3 = 72)
#define LADDR(lz,ly) ((lz)*PZ + (ly)*3)

// ---------------- threefry2x32, JAX partitionable scheme --------------------
__device__ __forceinline__ uint32_t rotl32(uint32_t x, uint32_t r) {
  return (x << r) | (x >> (32u - r));
}

__device__ __forceinline__ uint32_t threefry_bits(uint32_t idx) {
  const uint32_t ks0 = 0u, ks1 = 42u, ks2 = 0x1BD11BDAu ^ 0u ^ 42u;
  uint32_t x0 = 0u + ks0;
  uint32_t x1 = idx + ks1;
#define TFR(r) { x0 += x1; x1 = rotl32(x1, (r)); x1 ^= x0; }
  TFR(13u) TFR(15u) TFR(26u) TFR(6u)
  x0 += ks1; x1 += ks2 + 1u;
  TFR(17u) TFR(29u) TFR(16u) TFR(24u)
  x0 += ks2; x1 += ks0 + 2u;
  TFR(13u) TFR(15u) TFR(26u) TFR(6u)
  x0 += ks0; x1 += ks1 + 3u;
  TFR(17u) TFR(29u) TFR(16u) TFR(24u)
  x0 += ks1; x1 += ks2 + 4u;
  TFR(13u) TFR(15u) TFR(26u) TFR(6u)
  x0 += ks2; x1 += ks0 + 5u;
#undef TFR
  return x0 ^ x1;
}

// ------------- XLA-CPU (Cephes) float32 log replication ---------------------
__device__ __forceinline__ float xla_logf(float xin) {
  uint32_t bits = __float_as_uint(xin);
  float e = (float)((int)(bits >> 23) - 126);
  float x = __uint_as_float((bits & 0x007fffffu) | 0x3f000000u);
  const float SQRTHF = 0.707106781186547524f;
  bool lt = (x < SQRTHF);
  float tmp = lt ? x : 0.0f;
  e = e - (lt ? 1.0f : 0.0f);
  x = x - 1.0f;
  x = x + tmp;
  float z = x * x;
  float y = 7.0376836292e-2f;
  y = fmaf(y, x, -1.1514610310e-1f);
  y = fmaf(y, x,  1.1676998740e-1f);
  y = fmaf(y, x, -1.2420140846e-1f);
  y = fmaf(y, x,  1.4249322787e-1f);
  y = fmaf(y, x, -1.6668057665e-1f);
  y = fmaf(y, x,  2.0000714765e-1f);
  y = fmaf(y, x, -2.4999993993e-1f);
  y = fmaf(y, x,  3.3333331174e-1f);
  y = y * x;
  y = y * z;
  y = fmaf(e, -2.12194440e-4f, y);
  y = fmaf(-0.5f, z, y);
  x = x + y;
  x = fmaf(e, 0.693359375f, x);
  return x;
}

__device__ __forceinline__ float xla_log1pf(float x) {
  float for_large = xla_logf(x + 1.0f);
  float for_small = fmaf(-0.5f, x, 1.0f) * x;
  return (fabsf(x) < 1e-4f) ? for_small : for_large;
}

// one voxel's decision (exact JAX/XLA bit replication)
__device__ __forceinline__ bool bin_pred(const float* __restrict__ in, uint32_t w,
                                         uint32_t lane) {
  uint32_t row = w / 3u, wx = w - row * 3u;
  uint32_t n  = row / (uint32_t)(PDIM * PDIM);
  uint32_t rr = row - n * (uint32_t)(PDIM * PDIM);
  uint32_t z  = rr / (uint32_t)PDIM;
  uint32_t y  = rr - z * (uint32_t)PDIM;
  uint32_t x  = wx * 64u + lane;
  // pad voxels are provably 0: |0.33*noise| <= 6.08 < 18.42 = |log alpha(0)|
  if ((z - 1u) >= 160u || (y - 1u) >= 160u || (x - 1u) >= 160u) return false;
  float v = in[((n * 160u + (z - 1u)) * 160u + (y - 1u)) * 160u + (x - 1u)];
  uint32_t i = row * 162u + x;            // flat padded index for RNG
  uint32_t b = threefry_bits(i);
  float f  = __uint_as_float((b >> 9) | 0x3f800000u) - 1.0f;
  float uu = fmaxf(1e-8f, f + 1e-8f);
  float la = xla_logf((v + 1e-8f) / ((1.0f - v) + 1e-8f));
  float noise = xla_logf(uu) - xla_log1pf(-uu);
  float zs = la + noise * 0.33f;
  return (zs > 1.1920928955078125e-7f);   // logistic>0.5 iff z>2^-23
}

// ---------------------------- binarize --------------------------------------
// ILP-2: each wave produces TWO words (w and w+NW/2).
__global__ __launch_bounds__(256) void k_binarize(const float* __restrict__ in,
                                                  uint64_t* __restrict__ bits) {
  uint32_t t = blockIdx.x * 256u + threadIdx.x;
  uint32_t w0 = t >> 6, lane = t & 63u;
  if (w0 >= (uint32_t)NWH) return;        // wave-uniform
  uint32_t w1 = w0 + (uint32_t)NWH;
  bool p0 = bin_pred(in, w0, lane);
  bool p1 = bin_pred(in, w1, lane);
  uint64_t m0 = __ballot(p0);
  uint64_t m1 = __ballot(p1);
  if (lane == 0) { bits[w0] = m0; bits[w1] = m1; }
}

// ------------- per-word neighborhood from LDS row triples -------------------
#define NB(dz,dy,dx) ((dx)==-1 ? Lb[(dz)+1][(dy)+1] : ((dx)==1 ? Rb[(dz)+1][(dy)+1] : Vv[(dz)+1][(dy)+1]))

#define GATHER_W(SRC, lz, ly, w) \
  _Pragma("unroll") \
  for (int dz = 0; dz < 3; ++dz) \
    _Pragma("unroll") \
    for (int dy = 0; dy < 3; ++dy) { \
      int rb = LADDR((lz) + dz - 1, (ly) + dy - 1); \
      uint64_t r0 = SRC[rb], r1 = SRC[rb + 1], r2 = SRC[rb + 2]; \
      uint64_t b = ((w) == 0) ? r0 : (((w) == 1) ? r1 : r2); \
      uint64_t a = ((w) == 0) ? 0ull : (((w) == 1) ? r0 : r1); \
      uint64_t d = ((w) == 0) ? r1 : (((w) == 1) ? r2 : 0ull); \
      Vv[dz][dy] = b; \
      Lb[dz][dy] = (b << 1) | (a >> 63); \
      Rb[dz][dy] = (b >> 1) | (d << 63); \
    }

// ---- balanced (OR, GE2) reduction: low serial depth for latency hiding ----
struct OG { uint64_t o, g; };
__device__ __forceinline__ OG og_leaf2(uint64_t a, uint64_t b) {
  OG r; r.o = a | b; r.g = a & b; return r;
}
__device__ __forceinline__ OG og_comb(OG a, OG b) {
  OG r; r.g = a.g | b.g | (a.o & b.o); r.o = a.o | b.o; return r;
}

// OG over the 18-neighborhood (faces+edges) and corners; both trees depth ~4.
#define OG_BUILD_18_C(og18, ogc) \
  OG a0 = og_leaf2(NB(-1,0,0), NB(1,0,0)); \
  OG a1 = og_leaf2(NB(0,-1,0), NB(0,1,0)); \
  OG a2 = og_leaf2(NB(0,0,-1), NB(0,0,1)); \
  OG e0 = og_leaf2(NB(-1,-1,0), NB(-1,1,0)); \
  OG e1 = og_leaf2(NB(-1,0,-1), NB(-1,0,1)); \
  OG e2 = og_leaf2(NB(1,-1,0),  NB(1,1,0)); \
  OG e3 = og_leaf2(NB(1,0,-1),  NB(1,0,1)); \
  OG e4 = og_leaf2(NB(0,-1,-1), NB(0,-1,1)); \
  OG e5 = og_leaf2(NB(0,1,-1),  NB(0,1,1)); \
  OG t0 = og_comb(a0, a1); \
  OG t1 = og_comb(a2, e0); \
  OG t2 = og_comb(e1, e2); \
  OG t3 = og_comb(e3, e4); \
  OG og18 = og_comb(og_comb(og_comb(t0, t1), og_comb(t2, t3)), e5); \
  OG c0 = og_leaf2(NB(-1,-1,-1), NB(-1,-1,1)); \
  OG c1 = og_leaf2(NB(-1,1,-1),  NB(-1,1,1)); \
  OG c2 = og_leaf2(NB(1,-1,-1),  NB(1,-1,1)); \
  OG c3 = og_leaf2(NB(1,1,-1),   NB(1,1,1)); \
  OG ogc = og_comb(og_comb(c0, c1), og_comb(c2, c3));

// ---------------------------- iteration kernel ------------------------------
// One block: 8x8 (z,y) core x full 192-bit x, halo 8 -> 24x24 LDS tile.
// ge2 on halo 7, then 8 subfield passes with shrinking halo; writes core only
// (or, final iteration, the float output directly from LDS).
__global__ __launch_bounds__(NTHREADS) void k_iter(const uint64_t* __restrict__ bin,
                                                   uint64_t* __restrict__ bout,
                                                   float4* __restrict__ outf,
                                                   int zero_pads) {
  __shared__ uint64_t Bt[TZ * PZ];
  __shared__ uint64_t Ge[TZ * PZ];
  const int tid = threadIdx.x;
  const int bid = blockIdx.x;
  const int n  = bid / 400;
  const int rm = bid - n * 400;
  const int tz = rm / 20, ty = rm - tz * 20;
  const int gz0 = 1 + 8 * tz, gy0 = 1 + 8 * ty;
  // tile origin gz0-8 = 8*tz-7 is ODD for all tz -> PLZ/PLY parity mapping
  // below is tile-independent (same as the original 16x16 layout).

  // Zero bout's pad rows (z or y in {0,161}) once per replay (block 0, iter 1).
  if (zero_pads && bid == 0) {
    for (int j = tid; j < 1288; j += NTHREADS) {
      int nn, z, y;
      if (j < 648) { nn = j / 324; int r = j - nn * 324;
                     z = (r >= 162) ? 161 : 0; y = (r >= 162) ? r - 162 : r; }
      else { int j2 = j - 648; nn = j2 / 320; int r = j2 - nn * 320;
             y = (r >= 160) ? 161 : 0; z = 1 + ((r >= 160) ? r - 160 : r); }
      uint64_t* p = bout + (((nn * 162 + z) * 162) + y) * 3;
      p[0] = 0; p[1] = 0; p[2] = 0;
    }
  }

  // ---- load tile + halo 8 (w,ly fastest -> coalesced global reads) ----
  for (int ti = tid; ti < TZ * TY * 3; ti += NTHREADS) {
    int w = ti % 3, r = ti / 3, ly = r % TY, lz = r / TY;
    int z = gz0 - 8 + lz, y = gy0 - 8 + ly;
    uint64_t v = 0;
    if ((unsigned)z < 162u && (unsigned)y < 162u)
      v = bin[((n * 162 + z) * 162 + y) * 3 + w];
    Bt[LADDR(lz, ly) + w] = v;
  }
  __syncthreads();

  // ---- ge2 (C26>=2, not-endpoint) on halo 7 (22x22), tree reduction ----
  for (int ti = tid; ti < 22 * 22 * 3; ti += NTHREADS) {
    int w = ti % 3, r = ti / 3, iy = r % 22, iz = r / 22;
    int lz = 1 + iz, ly = 1 + iy;
    int base = LADDR(lz, ly) + w;
    uint64_t res = 0;
    if (Bt[base] != 0ull) {               // ge2 only consumed ANDed with center
      uint64_t Vv[3][3], Lb[3][3], Rb[3][3];
      GATHER_W(Bt, lz, ly, w)
      OG_BUILD_18_C(og18, ogc)
      res = og_comb(og18, ogc).g;         // GE2 over all 26
    }
    Ge[base] = res;
  }
  __syncthreads();

  // ---- 8 subfield passes, halo 7-k, parity per reference offsets order ----
  const int PLZ[8] = {1,0,1,0,1,0,1,0};   // lz parity (xo=0 -> z even -> lz odd)
  const int PLY[8] = {1,1,0,0,1,1,0,0};   // ly parity
#pragma unroll
  for (int k = 0; k < 8; ++k) {
    const int h = 7 - k;
    const int cnt1 = 4 + h;               // per-axis parity cells (core 8)
    const uint64_t xmask = (k < 4) ? 0x5555555555555555ull : 0xAAAAAAAAAAAAAAAAull;
    const int s0 = 8 - h;
    const int slz = s0 + ((s0 ^ PLZ[k]) & 1);
    const int sly = s0 + ((s0 ^ PLY[k]) & 1);
    for (int ti = tid; ti < cnt1 * cnt1 * 3; ti += NTHREADS) {
      int w = ti % 3, r = ti / 3, iy = r % cnt1, iz = r / cnt1;
      int lz = slz + 2 * iz, ly = sly + 2 * iy;
      int base = LADDR(lz, ly) + w;
      uint64_t center = Bt[base];
      uint64_t act = center & xmask & Ge[base];
      if (act == 0ull) continue;
      uint64_t Vv[3][3], Lb[3][3], Rb[3][3];
      GATHER_W(Bt, lz, ly, w)

      // tree (OR,GE2) over 18-set and corners
      OG_BUILD_18_C(og18, ogc)
      OG og26 = og_comb(og18, ogc);
      uint64_t e18 = og18.o & ~og18.g;    // C18 == 1
      uint64_t e26 = og26.o & ~og26.g;    // C26 == 1

      // C6 via complemented faces: eq5 = exactly-1 missing, le4 = >=2 missing
      uint64_t m0f = ~NB(-1,0,0), m1f = ~NB(1,0,0), m2f = ~NB(0,-1,0);
      uint64_t m3f = ~NB(0,1,0),  m4f = ~NB(0,0,-1), m5f = ~NB(0,0,1);
      OG p0 = og_leaf2(m0f, m1f);
      OG p1 = og_leaf2(m2f, m3f);
      OG p2 = og_leaf2(m4f, m5f);
      OG pm = og_comb(og_comb(p0, p1), p2);
      uint64_t c6eq5 = pm.o & ~pm.g;
      uint64_t c6le4 = pm.g;

      uint64_t del = (c6eq5 | e26) & act;
      // B/A patterns only where a candidate isn't already decided
      uint64_t need = act & ~del & (e18 | c6le4);
      if (need != 0ull) {
        // B: corner set with its 6 octant face/edge cells all clear
        uint64_t badB = 0;
#pragma unroll
        for (int sz = -1; sz <= 1; sz += 2)
#pragma unroll
          for (int sy = -1; sy <= 1; sy += 2)
#pragma unroll
            for (int sx = -1; sx <= 1; sx += 2) {
              uint64_t oct = NB(sz,0,0) | NB(0,sy,0) | NB(0,0,sx)
                           | NB(sz,sy,0) | NB(sz,0,sx) | NB(0,sy,sx);
              badB |= NB(sz,sy,sx) & ~oct;
            }
        uint64_t b0ok = ~badB;

        // A: face clear with its full 4-cell in-plane ring set
        uint64_t badA = 0;
        badA |= ~NB(-1,0,0) & NB(-1,-1,0) & NB(-1,1,0) & NB(-1,0,-1) & NB(-1,0,1);
        badA |= ~NB( 1,0,0) & NB( 1,-1,0) & NB( 1,1,0) & NB( 1,0,-1) & NB( 1,0,1);
        badA |= ~NB(0,-1,0) & NB(-1,-1,0) & NB(1,-1,0) & NB(0,-1,-1) & NB(0,-1,1);
        badA |= ~NB(0, 1,0) & NB(-1, 1,0) & NB(1, 1,0) & NB(0, 1,-1) & NB(0, 1,1);
        badA |= ~NB(0,0,-1) & NB(-1,0,-1) & NB(1,0,-1) & NB(0,-1,-1) & NB(0,1,-1);
        badA |= ~NB(0,0, 1) & NB(-1,0, 1) & NB(1,0, 1) & NB(0,-1, 1) & NB(0,1, 1);
        uint64_t a0ok = ~badA;

        del |= ((e18 & b0ok) | (c6le4 & a0ok & b0ok)) & act;
      }
      if (del) Bt[base] = center & ~del;
      // readers only consume non-updated-parity bits; tearing-safe (R5 arg)
    }
    __syncthreads();
  }

  // ---- epilogue ----
  if (outf) {
    // final iteration: write float output for core directly from LDS
    for (int ti = tid; ti < CZ * CY * 40; ti += NTHREADS) {
      int g = ti % 40, r = ti / 40, iy = r % CY, iz = r / CY;
      int base = LADDR(8 + iz, 8 + iy);
      int bi = 1 + 4 * g;                 // padded x of first of 4 floats
      int wx = bi >> 6, sft = bi & 63;
      uint64_t v = Bt[base + wx] >> sft;
      if (sft > 60) v |= Bt[base + wx + 1] << (64 - sft);
      outf[((n * 160 + (gz0 + iz - 1)) * 160 + (gy0 + iy - 1)) * 40 + g] =
          make_float4((float)(v & 1u), (float)((v >> 1) & 1u),
                      (float)((v >> 2) & 1u), (float)((v >> 3) & 1u));
    }
  } else {
    // write core words back (disjoint across blocks)
    for (int ti = tid; ti < CZ * CY * 3; ti += NTHREADS) {
      int w = ti % 3, r = ti / 3, iy = r % CY, iz = r / CY;
      bout[((n * 162 + gz0 + iz) * 162 + (gy0 + iy)) * 3 + w] =
          Bt[LADDR(8 + iz, 8 + iy) + w];
    }
  }
}

// ---------------------------- launcher --------------------------------------
extern "C" void kernel_launch(void* const* d_in, const int* in_sizes, int n_in,
                              void* d_out, int out_size, void* d_ws, size_t ws_size,
                              hipStream_t stream) {
  const float* in = (const float*)d_in[0];
  float4* out = (float4*)d_out;
  uint64_t* A = (uint64_t*)d_ws;          // bitboard A
  uint64_t* B = A + NW;                   // bitboard B

  k_binarize<<<dim3((NWH * 64 + 255) / 256), dim3(256), 0, stream>>>(in, A);
  k_iter<<<dim3(800), dim3(256), 0, stream>>>(A, B, nullptr, 1); // iter 1
  k_iter<<<dim3(800), dim3(256), 0, stream>>>(B, A, nullptr, 0); // iter 2
  k_iter<<<dim3(800), dim3(256), 0, stream>>>(A, B, nullptr, 0); // iter 3
  k_iter<<<dim3(800), dim3(256), 0, stream>>>(B, A, nullptr, 0); // iter 4
  k_iter<<<dim3(800), dim3(256), 0, stream>>>(A, nullptr, out, 0); // iter 5 -> out
}

// Round 3
// 275.602 us; speedup vs baseline: 1.2966x; 1.1034x over previous
//
#include <hip/hip_runtime.h>
#include <stdint.h>

// No implicit FMA contraction: the JAX eager reference has none across ops;
// where XLA fuses we write fmaf() explicitly.
#pragma clang fp contract(off)

#define PDIM 162
#define NW   (2*PDIM*PDIM*3)   // 157464 words, 1.26 MB per bitboard
#define NWH  (NW/2)            // 78732
#define OD   160

// R14: 16(z)x8(y) core, halo 8 -> 32x24 LDS tile, 512 threads, grid 400.
// Work = 1.43x R0 (vs R2's 1.94x at 8x8); 400 blocks x 8 waves, LDS 37.4KB
// -> 2-4 blocks/CU co-resident (desync doubles issue efficiency, R2 data).
// launch_bounds (512,4) caps VGPR at 128 (natural ~100) -- R1's (512,8)
// forced 32 and spilled (WRITE_SIZE 45MB); watch WRITE_SIZE ~1.4MB.
// ge2 is fused into the load phase, gathering the iteration-START board
// straight from global (L2-resident) -- removes the load->ge2 barrier and
// overlaps the two big latency phases.
#define NTHREADS 512
#define TZ 32                  // tile z rows (16 core + 2*8 halo)
#define TY 24                  // tile y rows ( 8 core + 2*8 halo)
#define CZ 16
#define CY 8
#define PZ 73                  // u64 per z-row (>= TY*3 = 72)
#define LADDR(lz,ly) ((lz)*PZ + (ly)*3)

// ---------------- threefry2x32, JAX partitionable scheme --------------------
__device__ __forceinline__ uint32_t rotl32(uint32_t x, uint32_t r) {
  return (x << r) | (x >> (32u - r));
}

__device__ __forceinline__ uint32_t threefry_bits(uint32_t idx) {
  const uint32_t ks0 = 0u, ks1 = 42u, ks2 = 0x1BD11BDAu ^ 0u ^ 42u;
  uint32_t x0 = 0u + ks0;
  uint32_t x1 = idx + ks1;
#define TFR(r) { x0 += x1; x1 = rotl32(x1, (r)); x1 ^= x0; }
  TFR(13u) TFR(15u) TFR(26u) TFR(6u)
  x0 += ks1; x1 += ks2 + 1u;
  TFR(17u) TFR(29u) TFR(16u) TFR(24u)
  x0 += ks2; x1 += ks0 + 2u;
  TFR(13u) TFR(15u) TFR(26u) TFR(6u)
  x0 += ks0; x1 += ks1 + 3u;
  TFR(17u) TFR(29u) TFR(16u) TFR(24u)
  x0 += ks1; x1 += ks2 + 4u;
  TFR(13u) TFR(15u) TFR(26u) TFR(6u)
  x0 += ks2; x1 += ks0 + 5u;
#undef TFR
  return x0 ^ x1;
}

// ------------- XLA-CPU (Cephes) float32 log replication ---------------------
__device__ __forceinline__ float xla_logf(float xin) {
  uint32_t bits = __float_as_uint(xin);
  float e = (float)((int)(bits >> 23) - 126);
  float x = __uint_as_float((bits & 0x007fffffu) | 0x3f000000u);
  const float SQRTHF = 0.707106781186547524f;
  bool lt = (x < SQRTHF);
  float tmp = lt ? x : 0.0f;
  e = e - (lt ? 1.0f : 0.0f);
  x = x - 1.0f;
  x = x + tmp;
  float z = x * x;
  float y = 7.0376836292e-2f;
  y = fmaf(y, x, -1.1514610310e-1f);
  y = fmaf(y, x,  1.1676998740e-1f);
  y = fmaf(y, x, -1.2420140846e-1f);
  y = fmaf(y, x,  1.4249322787e-1f);
  y = fmaf(y, x, -1.6668057665e-1f);
  y = fmaf(y, x,  2.0000714765e-1f);
  y = fmaf(y, x, -2.4999993993e-1f);
  y = fmaf(y, x,  3.3333331174e-1f);
  y = y * x;
  y = y * z;
  y = fmaf(e, -2.12194440e-4f, y);
  y = fmaf(-0.5f, z, y);
  x = x + y;
  x = fmaf(e, 0.693359375f, x);
  return x;
}

__device__ __forceinline__ float xla_log1pf(float x) {
  float for_large = xla_logf(x + 1.0f);
  float for_small = fmaf(-0.5f, x, 1.0f) * x;
  return (fabsf(x) < 1e-4f) ? for_small : for_large;
}

// one voxel's decision (exact JAX/XLA bit replication)
__device__ __forceinline__ bool bin_pred(const float* __restrict__ in, uint32_t w,
                                         uint32_t lane) {
  uint32_t row = w / 3u, wx = w - row * 3u;
  uint32_t n  = row / (uint32_t)(PDIM * PDIM);
  uint32_t rr = row - n * (uint32_t)(PDIM * PDIM);
  uint32_t z  = rr / (uint32_t)PDIM;
  uint32_t y  = rr - z * (uint32_t)PDIM;
  uint32_t x  = wx * 64u + lane;
  // pad voxels are provably 0: |0.33*noise| <= 6.08 < 18.42 = |log alpha(0)|
  if ((z - 1u) >= 160u || (y - 1u) >= 160u || (x - 1u) >= 160u) return false;
  float v = in[((n * 160u + (z - 1u)) * 160u + (y - 1u)) * 160u + (x - 1u)];
  uint32_t i = row * 162u + x;            // flat padded index for RNG
  uint32_t b = threefry_bits(i);
  float f  = __uint_as_float((b >> 9) | 0x3f800000u) - 1.0f;
  float uu = fmaxf(1e-8f, f + 1e-8f);
  float la = xla_logf((v + 1e-8f) / ((1.0f - v) + 1e-8f));
  float noise = xla_logf(uu) - xla_log1pf(-uu);
  float zs = la + noise * 0.33f;
  return (zs > 1.1920928955078125e-7f);   // logistic>0.5 iff z>2^-23
}

// ---------------------------- binarize --------------------------------------
// ILP-2: each wave produces TWO words (w and w+NW/2).
__global__ __launch_bounds__(256) void k_binarize(const float* __restrict__ in,
                                                  uint64_t* __restrict__ bits) {
  uint32_t t = blockIdx.x * 256u + threadIdx.x;
  uint32_t w0 = t >> 6, lane = t & 63u;
  if (w0 >= (uint32_t)NWH) return;        // wave-uniform
  uint32_t w1 = w0 + (uint32_t)NWH;
  bool p0 = bin_pred(in, w0, lane);
  bool p1 = bin_pred(in, w1, lane);
  uint64_t m0 = __ballot(p0);
  uint64_t m1 = __ballot(p1);
  if (lane == 0) { bits[w0] = m0; bits[w1] = m1; }
}

// ------------- per-word neighborhood from LDS row triples -------------------
#define NB(dz,dy,dx) ((dx)==-1 ? Lb[(dz)+1][(dy)+1] : ((dx)==1 ? Rb[(dz)+1][(dy)+1] : Vv[(dz)+1][(dy)+1]))

#define GATHER_W(SRC, lz, ly, w) \
  _Pragma("unroll") \
  for (int dz = 0; dz < 3; ++dz) \
    _Pragma("unroll") \
    for (int dy = 0; dy < 3; ++dy) { \
      int rb = LADDR((lz) + dz - 1, (ly) + dy - 1); \
      uint64_t r0 = SRC[rb], r1 = SRC[rb + 1], r2 = SRC[rb + 2]; \
      uint64_t b = ((w) == 0) ? r0 : (((w) == 1) ? r1 : r2); \
      uint64_t a = ((w) == 0) ? 0ull : (((w) == 1) ? r0 : r1); \
      uint64_t d = ((w) == 0) ? r1 : (((w) == 1) ? r2 : 0ull); \
      Vv[dz][dy] = b; \
      Lb[dz][dy] = (b << 1) | (a >> 63); \
      Rb[dz][dy] = (b >> 1) | (d << 63); \
    }

// ---- balanced (OR, GE2) reduction: low serial depth for latency hiding ----
struct OG { uint64_t o, g; };
__device__ __forceinline__ OG og_leaf2(uint64_t a, uint64_t b) {
  OG r; r.o = a | b; r.g = a & b; return r;
}
__device__ __forceinline__ OG og_comb(OG a, OG b) {
  OG r; r.g = a.g | b.g | (a.o & b.o); r.o = a.o | b.o; return r;
}

// OG over the 18-neighborhood (faces+edges) and corners; both trees depth ~4.
#define OG_BUILD_18_C(og18, ogc) \
  OG a0 = og_leaf2(NB(-1,0,0), NB(1,0,0)); \
  OG a1 = og_leaf2(NB(0,-1,0), NB(0,1,0)); \
  OG a2 = og_leaf2(NB(0,0,-1), NB(0,0,1)); \
  OG e0 = og_leaf2(NB(-1,-1,0), NB(-1,1,0)); \
  OG e1 = og_leaf2(NB(-1,0,-1), NB(-1,0,1)); \
  OG e2 = og_leaf2(NB(1,-1,0),  NB(1,1,0)); \
  OG e3 = og_leaf2(NB(1,0,-1),  NB(1,0,1)); \
  OG e4 = og_leaf2(NB(0,-1,-1), NB(0,-1,1)); \
  OG e5 = og_leaf2(NB(0,1,-1),  NB(0,1,1)); \
  OG t0 = og_comb(a0, a1); \
  OG t1 = og_comb(a2, e0); \
  OG t2 = og_comb(e1, e2); \
  OG t3 = og_comb(e3, e4); \
  OG og18 = og_comb(og_comb(og_comb(t0, t1), og_comb(t2, t3)), e5); \
  OG c0 = og_leaf2(NB(-1,-1,-1), NB(-1,-1,1)); \
  OG c1 = og_leaf2(NB(-1,1,-1),  NB(-1,1,1)); \
  OG c2 = og_leaf2(NB(1,-1,-1),  NB(1,-1,1)); \
  OG c3 = og_leaf2(NB(1,1,-1),   NB(1,1,1)); \
  OG ogc = og_comb(og_comb(c0, c1), og_comb(c2, c3));

// ---------------------------- iteration kernel ------------------------------
// One block: 16x8 (z,y) core x full 192-bit x, halo 8 -> 32x24 LDS tile.
// Fused phase 1: stage Bt loads into regs + ge2 (C26>=2) gathered from the
// GLOBAL iteration-start board (L2-resident) -> one barrier, overlap.
// Then 8 subfield passes with shrinking halo; writes core only (or, final
// iteration, the float output directly from LDS).
__global__ __launch_bounds__(NTHREADS, 4) void k_iter(const uint64_t* __restrict__ bin,
                                                      uint64_t* __restrict__ bout,
                                                      float4* __restrict__ outf,
                                                      int zero_pads) {
  __shared__ uint64_t Bt[TZ * PZ];
  __shared__ uint64_t Ge[TZ * PZ];
  const int tid = threadIdx.x;
  const int bid = blockIdx.x;
  const int n  = bid / 200;
  const int rm = bid - n * 200;
  const int tz = rm / 20, ty = rm - tz * 20;
  const int gz0 = 1 + 16 * tz, gy0 = 1 + 8 * ty;
  // tile origin gz0-8 (odd) and gy0-8 (odd) -> PLZ/PLY parity mapping below
  // is tile-independent (identical to the verified R1/R2 geometry).

  // Zero bout's pad rows (z or y in {0,161}) once per replay (block 0, iter 1).
  if (zero_pads && bid == 0) {
    for (int j = tid; j < 1288; j += NTHREADS) {
      int nn, z, y;
      if (j < 648) { nn = j / 324; int r = j - nn * 324;
                     z = (r >= 162) ? 161 : 0; y = (r >= 162) ? r - 162 : r; }
      else { int j2 = j - 648; nn = j2 / 320; int r = j2 - nn * 320;
             y = (r >= 160) ? 161 : 0; z = 1 + ((r >= 160) ? r - 160 : r); }
      uint64_t* p = bout + (((nn * 162 + z) * 162) + y) * 3;
      p[0] = 0; p[1] = 0; p[2] = 0;
    }
  }

  // ---- fused phase 1a: issue tile loads into registers (5 rounds) ----
  uint64_t stage[5];
#pragma unroll
  for (int s = 0; s < 5; ++s) {
    int ti = tid + s * NTHREADS;
    uint64_t v = 0;
    if (ti < TZ * TY * 3) {
      int w = ti % 3, r = ti / 3, ly = r % TY, lz = r / TY;
      int z = gz0 - 8 + lz, y = gy0 - 8 + ly;
      if ((unsigned)z < 162u && (unsigned)y < 162u)
        v = bin[((n * 162 + z) * 162 + y) * 3 + w];
    }
    stage[s] = v;
  }

  // ---- fused phase 1b: ge2 (C26>=2) on halo 7 (30x22), gathered from the
  // GLOBAL iteration-start board (== what the LDS tile would hold) ----
  for (int ti = tid; ti < 30 * 22 * 3; ti += NTHREADS) {
    int w = ti % 3, r = ti / 3, iy = r % 22, iz = r / 22;
    int zg = gz0 - 7 + iz, yg = gy0 - 7 + iy;
    uint64_t Vv[3][3], Lb[3][3], Rb[3][3];
#pragma unroll
    for (int dz = 0; dz < 3; ++dz)
#pragma unroll
      for (int dy = 0; dy < 3; ++dy) {
        int zr = zg - 1 + dz, yr = yg - 1 + dy;
        uint64_t r0 = 0, r1 = 0, r2 = 0;
        if ((unsigned)zr < 162u && (unsigned)yr < 162u) {
          const uint64_t* p = bin + ((n * 162 + zr) * 162 + yr) * 3;
          r0 = p[0]; r1 = p[1]; r2 = p[2];
        }
        uint64_t b = (w == 0) ? r0 : ((w == 1) ? r1 : r2);
        uint64_t a = (w == 0) ? 0ull : ((w == 1) ? r0 : r1);
        uint64_t d = (w == 0) ? r1 : ((w == 1) ? r2 : 0ull);
        Vv[dz][dy] = b;
        Lb[dz][dy] = (b << 1) | (a >> 63);
        Rb[dz][dy] = (b >> 1) | (d << 63);
      }
    uint64_t res = 0;
    if (Vv[1][1] != 0ull) {               // ge2 only consumed ANDed with center
      OG_BUILD_18_C(og18, ogc)
      res = og_comb(og18, ogc).g;         // GE2 over all 26
    }
    Ge[LADDR(1 + iz, 1 + iy) + w] = res;
  }

  // ---- fused phase 1c: commit staged Bt words to LDS ----
#pragma unroll
  for (int s = 0; s < 5; ++s) {
    int ti = tid + s * NTHREADS;
    if (ti < TZ * TY * 3) {
      int w = ti % 3, r = ti / 3, ly = r % TY, lz = r / TY;
      Bt[LADDR(lz, ly) + w] = stage[s];
    }
  }
  __syncthreads();

  // ---- 8 subfield passes, halo 7-k, parity per reference offsets order ----
  const int PLZ[8] = {1,0,1,0,1,0,1,0};   // lz parity (xo=0 -> z even -> lz odd)
  const int PLY[8] = {1,1,0,0,1,1,0,0};   // ly parity
#pragma unroll
  for (int k = 0; k < 8; ++k) {
    const int h = 7 - k;
    const int cntz = 8 + h, cnty = 4 + h;
    const uint64_t xmask = (k < 4) ? 0x5555555555555555ull : 0xAAAAAAAAAAAAAAAAull;
    const int s0 = 8 - h;
    const int slz = s0 + ((s0 ^ PLZ[k]) & 1);
    const int sly = s0 + ((s0 ^ PLY[k]) & 1);
    for (int ti = tid; ti < cntz * cnty * 3; ti += NTHREADS) {
      int w = ti % 3, r = ti / 3, iy = r % cnty, iz = r / cnty;
      int lz = slz + 2 * iz, ly = sly + 2 * iy;
      int base = LADDR(lz, ly) + w;
      uint64_t center = Bt[base];
      uint64_t act = center & xmask & Ge[base];
      if (act == 0ull) continue;
      uint64_t Vv[3][3], Lb[3][3], Rb[3][3];
      GATHER_W(Bt, lz, ly, w)

      // tree (OR,GE2) over 18-set and corners
      OG_BUILD_18_C(og18, ogc)
      OG og26 = og_comb(og18, ogc);
      uint64_t e18 = og18.o & ~og18.g;    // C18 == 1
      uint64_t e26 = og26.o & ~og26.g;    // C26 == 1

      // C6 via complemented faces: eq5 = exactly-1 missing, le4 = >=2 missing
      uint64_t m0f = ~NB(-1,0,0), m1f = ~NB(1,0,0), m2f = ~NB(0,-1,0);
      uint64_t m3f = ~NB(0,1,0),  m4f = ~NB(0,0,-1), m5f = ~NB(0,0,1);
      OG p0 = og_leaf2(m0f, m1f);
      OG p1 = og_leaf2(m2f, m3f);
      OG p2 = og_leaf2(m4f, m5f);
      OG pm = og_comb(og_comb(p0, p1), p2);
      uint64_t c6eq5 = pm.o & ~pm.g;
      uint64_t c6le4 = pm.g;

      uint64_t del = (c6eq5 | e26) & act;
      // B/A patterns only where a candidate isn't already decided
      uint64_t need = act & ~del & (e18 | c6le4);
      if (need != 0ull) {
        // B: corner set with its 6 octant face/edge cells all clear
        uint64_t badB = 0;
#pragma unroll
        for (int sz = -1; sz <= 1; sz += 2)
#pragma unroll
          for (int sy = -1; sy <= 1; sy += 2)
#pragma unroll
            for (int sx = -1; sx <= 1; sx += 2) {
              uint64_t oct = NB(sz,0,0) | NB(0,sy,0) | NB(0,0,sx)
                           | NB(sz,sy,0) | NB(sz,0,sx) | NB(0,sy,sx);
              badB |= NB(sz,sy,sx) & ~oct;
            }
        uint64_t b0ok = ~badB;

        // A: face clear with its full 4-cell in-plane ring set
        uint64_t badA = 0;
        badA |= ~NB(-1,0,0) & NB(-1,-1,0) & NB(-1,1,0) & NB(-1,0,-1) & NB(-1,0,1);
        badA |= ~NB( 1,0,0) & NB( 1,-1,0) & NB( 1,1,0) & NB( 1,0,-1) & NB( 1,0,1);
        badA |= ~NB(0,-1,0) & NB(-1,-1,0) & NB(1,-1,0) & NB(0,-1,-1) & NB(0,-1,1);
        badA |= ~NB(0, 1,0) & NB(-1, 1,0) & NB(1, 1,0) & NB(0, 1,-1) & NB(0, 1,1);
        badA |= ~NB(0,0,-1) & NB(-1,0,-1) & NB(1,0,-1) & NB(0,-1,-1) & NB(0,1,-1);
        badA |= ~NB(0,0, 1) & NB(-1,0, 1) & NB(1,0, 1) & NB(0,-1, 1) & NB(0,1, 1);
        uint64_t a0ok = ~badA;

        del |= ((e18 & b0ok) | (c6le4 & a0ok & b0ok)) & act;
      }
      if (del) Bt[base] = center & ~del;
      // readers only consume non-updated-parity bits; tearing-safe (R5 arg)
    }
    __syncthreads();
  }

  // ---- epilogue ----
  if (outf) {
    // final iteration: write float output for core directly from LDS
    for (int ti = tid; ti < CZ * CY * 40; ti += NTHREADS) {
      int g = ti % 40, r = ti / 40, iy = r % CY, iz = r / CY;
      int base = LADDR(8 + iz, 8 + iy);
      int bi = 1 + 4 * g;                 // padded x of first of 4 floats
      int wx = bi >> 6, sft = bi & 63;
      uint64_t v = Bt[base + wx] >> sft;
      if (sft > 60) v |= Bt[base + wx + 1] << (64 - sft);
      outf[((n * 160 + (gz0 + iz - 1)) * 160 + (gy0 + iy - 1)) * 40 + g] =
          make_float4((float)(v & 1u), (float)((v >> 1) & 1u),
                      (float)((v >> 2) & 1u), (float)((v >> 3) & 1u));
    }
  } else {
    // write core words back (disjoint across blocks)
    for (int ti = tid; ti < CZ * CY * 3; ti += NTHREADS) {
      int w = ti % 3, r = ti / 3, iy = r % CY, iz = r / CY;
      bout[((n * 162 + gz0 + iz) * 162 + (gy0 + iy)) * 3 + w] =
          Bt[LADDR(8 + iz, 8 + iy) + w];
    }
  }
}

// ---------------------------- launcher --------------------------------------
extern "C" void kernel_launch(void* const* d_in, const int* in_sizes, int n_in,
                              void* d_out, int out_size, void* d_ws, size_t ws_size,
                              hipStream_t stream) {
  const float* in = (const float*)d_in[0];
  float4* out = (float4*)d_out;
  uint64_t* A = (uint64_t*)d_ws;          // bitboard A
  uint64_t* B = A + NW;                   // bitboard B

  k_binarize<<<dim3((NWH * 64 + 255) / 256), dim3(256), 0, stream>>>(in, A);
  k_iter<<<dim3(400), dim3(NTHREADS), 0, stream>>>(A, B, nullptr, 1); // iter 1
  k_iter<<<dim3(400), dim3(NTHREADS), 0, stream>>>(B, A, nullptr, 0); // iter 2
  k_iter<<<dim3(400), dim3(NTHREADS), 0, stream>>>(A, B, nullptr, 0); // iter 3
  k_iter<<<dim3(400), dim3(NTHREADS), 0, stream>>>(B, A, nullptr, 0); // iter 4
  k_iter<<<dim3(400), dim3(NTHREADS), 0, stream>>>(A, nullptr, out, 0); // iter 5 -> out
}

// Round 4
// 234.399 us; speedup vs baseline: 1.5245x; 1.1758x over previous
//
#include <hip/hip_runtime.h>
#include <stdint.h>

// No implicit FMA contraction: the JAX eager reference has none across ops;
// where XLA fuses we write fmaf() explicitly.
#pragma clang fp contract(off)

#define PDIM 162
#define NW   (2*PDIM*PDIM*3)   // 157464 words, 1.26 MB per bitboard
#define NWH  (NW/2)            // 78732
#define OD   160

// R15: back to the measured-best R0 geometry (16x16 core, halo 8 -> 32x32
// tile, 1024 threads, grid 200; real ~32us/iter, lowest halo redundancy:
// 1.97M items/iter vs 2.75M @16x8, 4.7M @8x8 -- R1-R3 showed redundancy
// costs linearly and dominates occupancy-desync gains). Grafted on top: the
// R3-proven ge2-from-global fusion -- phase 1 issues tile loads into regs,
// gathers ge2 straight from the L2-resident global board (overlapping the
// staging latency), commits, ONE barrier instead of two.
// NO min-occupancy launch bound (R1's (512,8) forced VGPR=32 -> scratch
// spill, WRITE_SIZE 1.3->45MB). Guard metric: WRITE_SIZE ~1.34MB.
#define NTHREADS 1024
#define TZ 32                  // tile z rows (16 core + 2*8 halo)
#define TY 32                  // tile y rows (16 core + 2*8 halo)
#define CZ 16
#define CY 16
// 97 u64 = 194 dwords == 2 mod 32 (measured conflict-neutral, R11).
#define PZ 97
#define LADDR(lz,ly) ((lz)*PZ + (ly)*3)

// ---------------- threefry2x32, JAX partitionable scheme --------------------
__device__ __forceinline__ uint32_t rotl32(uint32_t x, uint32_t r) {
  return (x << r) | (x >> (32u - r));
}

__device__ __forceinline__ uint32_t threefry_bits(uint32_t idx) {
  const uint32_t ks0 = 0u, ks1 = 42u, ks2 = 0x1BD11BDAu ^ 0u ^ 42u;
  uint32_t x0 = 0u + ks0;
  uint32_t x1 = idx + ks1;
#define TFR(r) { x0 += x1; x1 = rotl32(x1, (r)); x1 ^= x0; }
  TFR(13u) TFR(15u) TFR(26u) TFR(6u)
  x0 += ks1; x1 += ks2 + 1u;
  TFR(17u) TFR(29u) TFR(16u) TFR(24u)
  x0 += ks2; x1 += ks0 + 2u;
  TFR(13u) TFR(15u) TFR(26u) TFR(6u)
  x0 += ks0; x1 += ks1 + 3u;
  TFR(17u) TFR(29u) TFR(16u) TFR(24u)
  x0 += ks1; x1 += ks2 + 4u;
  TFR(13u) TFR(15u) TFR(26u) TFR(6u)
  x0 += ks2; x1 += ks0 + 5u;
#undef TFR
  return x0 ^ x1;
}

// ------------- XLA-CPU (Cephes) float32 log replication ---------------------
__device__ __forceinline__ float xla_logf(float xin) {
  uint32_t bits = __float_as_uint(xin);
  float e = (float)((int)(bits >> 23) - 126);
  float x = __uint_as_float((bits & 0x007fffffu) | 0x3f000000u);
  const float SQRTHF = 0.707106781186547524f;
  bool lt = (x < SQRTHF);
  float tmp = lt ? x : 0.0f;
  e = e - (lt ? 1.0f : 0.0f);
  x = x - 1.0f;
  x = x + tmp;
  float z = x * x;
  float y = 7.0376836292e-2f;
  y = fmaf(y, x, -1.1514610310e-1f);
  y = fmaf(y, x,  1.1676998740e-1f);
  y = fmaf(y, x, -1.2420140846e-1f);
  y = fmaf(y, x,  1.4249322787e-1f);
  y = fmaf(y, x, -1.6668057665e-1f);
  y = fmaf(y, x,  2.0000714765e-1f);
  y = fmaf(y, x, -2.4999993993e-1f);
  y = fmaf(y, x,  3.3333331174e-1f);
  y = y * x;
  y = y * z;
  y = fmaf(e, -2.12194440e-4f, y);
  y = fmaf(-0.5f, z, y);
  x = x + y;
  x = fmaf(e, 0.693359375f, x);
  return x;
}

__device__ __forceinline__ float xla_log1pf(float x) {
  float for_large = xla_logf(x + 1.0f);
  float for_small = fmaf(-0.5f, x, 1.0f) * x;
  return (fabsf(x) < 1e-4f) ? for_small : for_large;
}

// one voxel's decision (exact JAX/XLA bit replication)
__device__ __forceinline__ bool bin_pred(const float* __restrict__ in, uint32_t w,
                                         uint32_t lane) {
  uint32_t row = w / 3u, wx = w - row * 3u;
  uint32_t n  = row / (uint32_t)(PDIM * PDIM);
  uint32_t rr = row - n * (uint32_t)(PDIM * PDIM);
  uint32_t z  = rr / (uint32_t)PDIM;
  uint32_t y  = rr - z * (uint32_t)PDIM;
  uint32_t x  = wx * 64u + lane;
  // pad voxels are provably 0: |0.33*noise| <= 6.08 < 18.42 = |log alpha(0)|
  if ((z - 1u) >= 160u || (y - 1u) >= 160u || (x - 1u) >= 160u) return false;
  float v = in[((n * 160u + (z - 1u)) * 160u + (y - 1u)) * 160u + (x - 1u)];
  uint32_t i = row * 162u + x;            // flat padded index for RNG
  uint32_t b = threefry_bits(i);
  float f  = __uint_as_float((b >> 9) | 0x3f800000u) - 1.0f;
  float uu = fmaxf(1e-8f, f + 1e-8f);
  float la = xla_logf((v + 1e-8f) / ((1.0f - v) + 1e-8f));
  float noise = xla_logf(uu) - xla_log1pf(-uu);
  float zs = la + noise * 0.33f;
  return (zs > 1.1920928955078125e-7f);   // logistic>0.5 iff z>2^-23
}

// ---------------------------- binarize --------------------------------------
// ILP-2: each wave produces TWO words (w and w+NW/2).
__global__ __launch_bounds__(256) void k_binarize(const float* __restrict__ in,
                                                  uint64_t* __restrict__ bits) {
  uint32_t t = blockIdx.x * 256u + threadIdx.x;
  uint32_t w0 = t >> 6, lane = t & 63u;
  if (w0 >= (uint32_t)NWH) return;        // wave-uniform
  uint32_t w1 = w0 + (uint32_t)NWH;
  bool p0 = bin_pred(in, w0, lane);
  bool p1 = bin_pred(in, w1, lane);
  uint64_t m0 = __ballot(p0);
  uint64_t m1 = __ballot(p1);
  if (lane == 0) { bits[w0] = m0; bits[w1] = m1; }
}

// ------------- per-word neighborhood from LDS row triples -------------------
#define NB(dz,dy,dx) ((dx)==-1 ? Lb[(dz)+1][(dy)+1] : ((dx)==1 ? Rb[(dz)+1][(dy)+1] : Vv[(dz)+1][(dy)+1]))

#define GATHER_W(SRC, lz, ly, w) \
  _Pragma("unroll") \
  for (int dz = 0; dz < 3; ++dz) \
    _Pragma("unroll") \
    for (int dy = 0; dy < 3; ++dy) { \
      int rb = LADDR((lz) + dz - 1, (ly) + dy - 1); \
      uint64_t r0 = SRC[rb], r1 = SRC[rb + 1], r2 = SRC[rb + 2]; \
      uint64_t b = ((w) == 0) ? r0 : (((w) == 1) ? r1 : r2); \
      uint64_t a = ((w) == 0) ? 0ull : (((w) == 1) ? r0 : r1); \
      uint64_t d = ((w) == 0) ? r1 : (((w) == 1) ? r2 : 0ull); \
      Vv[dz][dy] = b; \
      Lb[dz][dy] = (b << 1) | (a >> 63); \
      Rb[dz][dy] = (b >> 1) | (d << 63); \
    }

// ---- balanced (OR, GE2) reduction: low serial depth for latency hiding ----
struct OG { uint64_t o, g; };
__device__ __forceinline__ OG og_leaf2(uint64_t a, uint64_t b) {
  OG r; r.o = a | b; r.g = a & b; return r;
}
__device__ __forceinline__ OG og_comb(OG a, OG b) {
  OG r; r.g = a.g | b.g | (a.o & b.o); r.o = a.o | b.o; return r;
}

// OG over the 18-neighborhood (faces+edges) and corners; both trees depth ~4.
#define OG_BUILD_18_C(og18, ogc) \
  OG a0 = og_leaf2(NB(-1,0,0), NB(1,0,0)); \
  OG a1 = og_leaf2(NB(0,-1,0), NB(0,1,0)); \
  OG a2 = og_leaf2(NB(0,0,-1), NB(0,0,1)); \
  OG e0 = og_leaf2(NB(-1,-1,0), NB(-1,1,0)); \
  OG e1 = og_leaf2(NB(-1,0,-1), NB(-1,0,1)); \
  OG e2 = og_leaf2(NB(1,-1,0),  NB(1,1,0)); \
  OG e3 = og_leaf2(NB(1,0,-1),  NB(1,0,1)); \
  OG e4 = og_leaf2(NB(0,-1,-1), NB(0,-1,1)); \
  OG e5 = og_leaf2(NB(0,1,-1),  NB(0,1,1)); \
  OG t0 = og_comb(a0, a1); \
  OG t1 = og_comb(a2, e0); \
  OG t2 = og_comb(e1, e2); \
  OG t3 = og_comb(e3, e4); \
  OG og18 = og_comb(og_comb(og_comb(t0, t1), og_comb(t2, t3)), e5); \
  OG c0 = og_leaf2(NB(-1,-1,-1), NB(-1,-1,1)); \
  OG c1 = og_leaf2(NB(-1,1,-1),  NB(-1,1,1)); \
  OG c2 = og_leaf2(NB(1,-1,-1),  NB(1,-1,1)); \
  OG c3 = og_leaf2(NB(1,1,-1),   NB(1,1,1)); \
  OG ogc = og_comb(og_comb(c0, c1), og_comb(c2, c3));

// ---------------------------- iteration kernel ------------------------------
// One block: 16x16 (z,y) core x full 192-bit x, halo 8 -> 32x32 LDS tile.
// Fused phase 1: stage tile loads into regs + ge2 (C26>=2) gathered from the
// GLOBAL iteration-start board (L2-resident) -> one barrier, overlap.
// Then 8 subfield passes with shrinking halo; writes core only (or, final
// iteration, the float output directly from LDS).
__global__ __launch_bounds__(NTHREADS) void k_iter(const uint64_t* __restrict__ bin,
                                                   uint64_t* __restrict__ bout,
                                                   float4* __restrict__ outf,
                                                   int zero_pads) {
  __shared__ uint64_t Bt[TZ * PZ];
  __shared__ uint64_t Ge[TZ * PZ];
  const int tid = threadIdx.x;
  const int bid = blockIdx.x;
  const int n  = bid / 100;
  const int rm = bid - n * 100;
  const int tz = rm / 10, ty = rm - tz * 10;
  const int gz0 = 1 + 16 * tz, gy0 = 1 + 16 * ty;   // both odd

  // Zero bout's pad rows (z or y in {0,161}) once per replay (block 0, iter 1).
  if (zero_pads && bid == 0) {
    for (int j = tid; j < 1288; j += NTHREADS) {
      int nn, z, y;
      if (j < 648) { nn = j / 324; int r = j - nn * 324;
                     z = (r >= 162) ? 161 : 0; y = (r >= 162) ? r - 162 : r; }
      else { int j2 = j - 648; nn = j2 / 320; int r = j2 - nn * 320;
             y = (r >= 160) ? 161 : 0; z = 1 + ((r >= 160) ? r - 160 : r); }
      uint64_t* p = bout + (((nn * 162 + z) * 162) + y) * 3;
      p[0] = 0; p[1] = 0; p[2] = 0;
    }
  }

  // ---- fused phase 1a: issue tile loads into registers (exactly 3 rounds,
  // 32*32*3 == 3*NTHREADS; w,ly fastest -> coalesced) ----
  uint64_t stage[3];
#pragma unroll
  for (int s = 0; s < 3; ++s) {
    int ti = tid + s * NTHREADS;
    int w = ti % 3, r = ti / 3, ly = r % TY, lz = r / TY;
    int z = gz0 - 8 + lz, y = gy0 - 8 + ly;
    uint64_t v = 0;
    if ((unsigned)z < 162u && (unsigned)y < 162u)
      v = bin[((n * 162 + z) * 162 + y) * 3 + w];
    stage[s] = v;
  }

  // ---- fused phase 1b: ge2 (C26>=2) on halo 7 (30x30), gathered from the
  // GLOBAL iteration-start board (== what the LDS tile will hold); its L2
  // traffic overlaps the staging loads' latency ----
  for (int ti = tid; ti < 30 * 30 * 3; ti += NTHREADS) {
    int w = ti % 3, r = ti / 3, iy = r % 30, iz = r / 30;
    int zg = gz0 - 7 + iz, yg = gy0 - 7 + iy;
    uint64_t Vv[3][3], Lb[3][3], Rb[3][3];
#pragma unroll
    for (int dz = 0; dz < 3; ++dz)
#pragma unroll
      for (int dy = 0; dy < 3; ++dy) {
        int zr = zg - 1 + dz, yr = yg - 1 + dy;
        uint64_t r0 = 0, r1 = 0, r2 = 0;
        if ((unsigned)zr < 162u && (unsigned)yr < 162u) {
          const uint64_t* p = bin + ((n * 162 + zr) * 162 + yr) * 3;
          r0 = p[0]; r1 = p[1]; r2 = p[2];
        }
        uint64_t b = (w == 0) ? r0 : ((w == 1) ? r1 : r2);
        uint64_t a = (w == 0) ? 0ull : ((w == 1) ? r0 : r1);
        uint64_t d = (w == 0) ? r1 : ((w == 1) ? r2 : 0ull);
        Vv[dz][dy] = b;
        Lb[dz][dy] = (b << 1) | (a >> 63);
        Rb[dz][dy] = (b >> 1) | (d << 63);
      }
    uint64_t res = 0;
    if (Vv[1][1] != 0ull) {               // ge2 only consumed ANDed with center
      OG_BUILD_18_C(og18, ogc)
      res = og_comb(og18, ogc).g;         // GE2 over all 26
    }
    Ge[LADDR(1 + iz, 1 + iy) + w] = res;
  }

  // ---- fused phase 1c: commit staged Bt words to LDS ----
#pragma unroll
  for (int s = 0; s < 3; ++s) {
    int ti = tid + s * NTHREADS;
    int w = ti % 3, r = ti / 3, ly = r % TY, lz = r / TY;
    Bt[LADDR(lz, ly) + w] = stage[s];
  }
  __syncthreads();

  // ---- 8 subfield passes, halo 7-k, parity per reference offsets order ----
  const int PLZ[8] = {1,0,1,0,1,0,1,0};   // lz parity (xo=0 -> z even -> lz odd)
  const int PLY[8] = {1,1,0,0,1,1,0,0};   // ly parity
#pragma unroll
  for (int k = 0; k < 8; ++k) {
    const int h = 7 - k, cnt1 = 8 + h;
    const uint64_t xmask = (k < 4) ? 0x5555555555555555ull : 0xAAAAAAAAAAAAAAAAull;
    const int s0 = 8 - h;
    const int slz = s0 + ((s0 ^ PLZ[k]) & 1);
    const int sly = s0 + ((s0 ^ PLY[k]) & 1);
    for (int ti = tid; ti < cnt1 * cnt1 * 3; ti += NTHREADS) {
      int w = ti % 3, r = ti / 3, iy = r % cnt1, iz = r / cnt1;
      int lz = slz + 2 * iz, ly = sly + 2 * iy;
      int base = LADDR(lz, ly) + w;
      uint64_t center = Bt[base];
      uint64_t act = center & xmask & Ge[base];
      if (act == 0ull) continue;
      uint64_t Vv[3][3], Lb[3][3], Rb[3][3];
      GATHER_W(Bt, lz, ly, w)

      // tree (OR,GE2) over 18-set and corners
      OG_BUILD_18_C(og18, ogc)
      OG og26 = og_comb(og18, ogc);
      uint64_t e18 = og18.o & ~og18.g;    // C18 == 1
      uint64_t e26 = og26.o & ~og26.g;    // C26 == 1

      // C6 via complemented faces: eq5 = exactly-1 missing, le4 = >=2 missing
      uint64_t m0f = ~NB(-1,0,0), m1f = ~NB(1,0,0), m2f = ~NB(0,-1,0);
      uint64_t m3f = ~NB(0,1,0),  m4f = ~NB(0,0,-1), m5f = ~NB(0,0,1);
      OG p0 = og_leaf2(m0f, m1f);
      OG p1 = og_leaf2(m2f, m3f);
      OG p2 = og_leaf2(m4f, m5f);
      OG pm = og_comb(og_comb(p0, p1), p2);
      uint64_t c6eq5 = pm.o & ~pm.g;
      uint64_t c6le4 = pm.g;

      uint64_t del = (c6eq5 | e26) & act;
      // B/A patterns only where a candidate isn't already decided
      uint64_t need = act & ~del & (e18 | c6le4);
      if (need != 0ull) {
        // B: corner set with its 6 octant face/edge cells all clear
        uint64_t badB = 0;
#pragma unroll
        for (int sz = -1; sz <= 1; sz += 2)
#pragma unroll
          for (int sy = -1; sy <= 1; sy += 2)
#pragma unroll
            for (int sx = -1; sx <= 1; sx += 2) {
              uint64_t oct = NB(sz,0,0) | NB(0,sy,0) | NB(0,0,sx)
                           | NB(sz,sy,0) | NB(sz,0,sx) | NB(0,sy,sx);
              badB |= NB(sz,sy,sx) & ~oct;
            }
        uint64_t b0ok = ~badB;

        // A: face clear with its full 4-cell in-plane ring set
        uint64_t badA = 0;
        badA |= ~NB(-1,0,0) & NB(-1,-1,0) & NB(-1,1,0) & NB(-1,0,-1) & NB(-1,0,1);
        badA |= ~NB( 1,0,0) & NB( 1,-1,0) & NB( 1,1,0) & NB( 1,0,-1) & NB( 1,0,1);
        badA |= ~NB(0,-1,0) & NB(-1,-1,0) & NB(1,-1,0) & NB(0,-1,-1) & NB(0,-1,1);
        badA |= ~NB(0, 1,0) & NB(-1, 1,0) & NB(1, 1,0) & NB(0, 1,-1) & NB(0, 1,1);
        badA |= ~NB(0,0,-1) & NB(-1,0,-1) & NB(1,0,-1) & NB(0,-1,-1) & NB(0,1,-1);
        badA |= ~NB(0,0, 1) & NB(-1,0, 1) & NB(1,0, 1) & NB(0,-1, 1) & NB(0,1, 1);
        uint64_t a0ok = ~badA;

        del |= ((e18 & b0ok) | (c6le4 & a0ok & b0ok)) & act;
      }
      if (del) Bt[base] = center & ~del;
      // readers only consume non-updated-parity bits; tearing-safe (R5 arg)
    }
    __syncthreads();
  }

  // ---- epilogue ----
  if (outf) {
    // final iteration: write float output for core directly from LDS
    for (int ti = tid; ti < CZ * CY * 40; ti += NTHREADS) {
      int g = ti % 40, r = ti / 40, iy = r % CY, iz = r / CY;
      int base = LADDR(8 + iz, 8 + iy);
      int bi = 1 + 4 * g;                 // padded x of first of 4 floats
      int wx = bi >> 6, sft = bi & 63;
      uint64_t v = Bt[base + wx] >> sft;
      if (sft > 60) v |= Bt[base + wx + 1] << (64 - sft);
      outf[((n * 160 + (gz0 + iz - 1)) * 160 + (gy0 + iy - 1)) * 40 + g] =
          make_float4((float)(v & 1u), (float)((v >> 1) & 1u),
                      (float)((v >> 2) & 1u), (float)((v >> 3) & 1u));
    }
  } else {
    // write core words back (disjoint across blocks)
    for (int ti = tid; ti < CZ * CY * 3; ti += NTHREADS) {
      int w = ti % 3, r = ti / 3, iy = r % CY, iz = r / CY;
      bout[((n * 162 + gz0 + iz) * 162 + (gy0 + iy)) * 3 + w] =
          Bt[LADDR(8 + iz, 8 + iy) + w];
    }
  }
}

// ---------------------------- launcher --------------------------------------
extern "C" void kernel_launch(void* const* d_in, const int* in_sizes, int n_in,
                              void* d_out, int out_size, void* d_ws, size_t ws_size,
                              hipStream_t stream) {
  const float* in = (const float*)d_in[0];
  float4* out = (float4*)d_out;
  uint64_t* A = (uint64_t*)d_ws;          // bitboard A
  uint64_t* B = A + NW;                   // bitboard B

  k_binarize<<<dim3((NWH * 64 + 255) / 256), dim3(256), 0, stream>>>(in, A);
  k_iter<<<dim3(200), dim3(NTHREADS), 0, stream>>>(A, B, nullptr, 1); // iter 1
  k_iter<<<dim3(200), dim3(NTHREADS), 0, stream>>>(B, A, nullptr, 0); // iter 2
  k_iter<<<dim3(200), dim3(NTHREADS), 0, stream>>>(A, B, nullptr, 0); // iter 3
  k_iter<<<dim3(200), dim3(NTHREADS), 0, stream>>>(B, A, nullptr, 0); // iter 4
  k_iter<<<dim3(200), dim3(NTHREADS), 0, stream>>>(A, nullptr, out, 0); // iter 5 -> out
}

// Round 5
// 224.650 us; speedup vs baseline: 1.5907x; 1.0434x over previous
//
#include <hip/hip_runtime.h>
#include <stdint.h>

// No implicit FMA contraction: the JAX eager reference has none across ops;
// where XLA fuses we write fmaf() explicitly.
#pragma clang fp contract(off)

#define PDIM 162
#define NW   (2*PDIM*PDIM*3)   // 157464 words, 1.26 MB per bitboard
#define NWH  (NW/2)            // 78732
#define OD   160

// R16: R0 geometry exactly (measured best: 220.8us; 16x16 core, halo 8,
// 32x32 tile, 1024 threads, grid 200) with ONE change: GATHER_W is
// restructured to load all 27 neighborhood words into explicit locals
// FIRST, then compute. At R0's VGPR=48 the compiler couldn't batch the 27
// ds_reads (27 u64 = 54 VGPR > budget) and serialized them into dependent
// ~120cyc lgkmcnt waits -- the measured 5x gap between VALU work (18% busy)
// and duration. Wide live ranges force a bigger allocation (512 available
// at 16 waves/CU) and one wait per gather instead of ~dozen.
// Confirmation signal: VGPR_Count ~90-130. Guard: WRITE_SIZE ~1.34MB
// (jump = scratch spill, the R1 failure mode).
#define NTHREADS 1024
#define TZ 32
#define TY 32
#define CZ 16
#define CY 16
// 97 u64 = 194 dwords == 2 mod 32 (measured conflict-neutral, R11).
#define PZ 97
#define LADDR(lz,ly) ((lz)*PZ + (ly)*3)

// ---------------- threefry2x32, JAX partitionable scheme --------------------
__device__ __forceinline__ uint32_t rotl32(uint32_t x, uint32_t r) {
  return (x << r) | (x >> (32u - r));
}

__device__ __forceinline__ uint32_t threefry_bits(uint32_t idx) {
  const uint32_t ks0 = 0u, ks1 = 42u, ks2 = 0x1BD11BDAu ^ 0u ^ 42u;
  uint32_t x0 = 0u + ks0;
  uint32_t x1 = idx + ks1;
#define TFR(r) { x0 += x1; x1 = rotl32(x1, (r)); x1 ^= x0; }
  TFR(13u) TFR(15u) TFR(26u) TFR(6u)
  x0 += ks1; x1 += ks2 + 1u;
  TFR(17u) TFR(29u) TFR(16u) TFR(24u)
  x0 += ks2; x1 += ks0 + 2u;
  TFR(13u) TFR(15u) TFR(26u) TFR(6u)
  x0 += ks0; x1 += ks1 + 3u;
  TFR(17u) TFR(29u) TFR(16u) TFR(24u)
  x0 += ks1; x1 += ks2 + 4u;
  TFR(13u) TFR(15u) TFR(26u) TFR(6u)
  x0 += ks2; x1 += ks0 + 5u;
#undef TFR
  return x0 ^ x1;
}

// ------------- XLA-CPU (Cephes) float32 log replication ---------------------
__device__ __forceinline__ float xla_logf(float xin) {
  uint32_t bits = __float_as_uint(xin);
  float e = (float)((int)(bits >> 23) - 126);
  float x = __uint_as_float((bits & 0x007fffffu) | 0x3f000000u);
  const float SQRTHF = 0.707106781186547524f;
  bool lt = (x < SQRTHF);
  float tmp = lt ? x : 0.0f;
  e = e - (lt ? 1.0f : 0.0f);
  x = x - 1.0f;
  x = x + tmp;
  float z = x * x;
  float y = 7.0376836292e-2f;
  y = fmaf(y, x, -1.1514610310e-1f);
  y = fmaf(y, x,  1.1676998740e-1f);
  y = fmaf(y, x, -1.2420140846e-1f);
  y = fmaf(y, x,  1.4249322787e-1f);
  y = fmaf(y, x, -1.6668057665e-1f);
  y = fmaf(y, x,  2.0000714765e-1f);
  y = fmaf(y, x, -2.4999993993e-1f);
  y = fmaf(y, x,  3.3333331174e-1f);
  y = y * x;
  y = y * z;
  y = fmaf(e, -2.12194440e-4f, y);
  y = fmaf(-0.5f, z, y);
  x = x + y;
  x = fmaf(e, 0.693359375f, x);
  return x;
}

__device__ __forceinline__ float xla_log1pf(float x) {
  float for_large = xla_logf(x + 1.0f);
  float for_small = fmaf(-0.5f, x, 1.0f) * x;
  return (fabsf(x) < 1e-4f) ? for_small : for_large;
}

// one voxel's decision (exact JAX/XLA bit replication)
__device__ __forceinline__ bool bin_pred(const float* __restrict__ in, uint32_t w,
                                         uint32_t lane) {
  uint32_t row = w / 3u, wx = w - row * 3u;
  uint32_t n  = row / (uint32_t)(PDIM * PDIM);
  uint32_t rr = row - n * (uint32_t)(PDIM * PDIM);
  uint32_t z  = rr / (uint32_t)PDIM;
  uint32_t y  = rr - z * (uint32_t)PDIM;
  uint32_t x  = wx * 64u + lane;
  // pad voxels are provably 0: |0.33*noise| <= 6.08 < 18.42 = |log alpha(0)|
  if ((z - 1u) >= 160u || (y - 1u) >= 160u || (x - 1u) >= 160u) return false;
  float v = in[((n * 160u + (z - 1u)) * 160u + (y - 1u)) * 160u + (x - 1u)];
  uint32_t i = row * 162u + x;            // flat padded index for RNG
  uint32_t b = threefry_bits(i);
  float f  = __uint_as_float((b >> 9) | 0x3f800000u) - 1.0f;
  float uu = fmaxf(1e-8f, f + 1e-8f);
  float la = xla_logf((v + 1e-8f) / ((1.0f - v) + 1e-8f));
  float noise = xla_logf(uu) - xla_log1pf(-uu);
  float zs = la + noise * 0.33f;
  return (zs > 1.1920928955078125e-7f);   // logistic>0.5 iff z>2^-23
}

// ---------------------------- binarize --------------------------------------
// ILP-2: each wave produces TWO words (w and w+NW/2).
__global__ __launch_bounds__(256) void k_binarize(const float* __restrict__ in,
                                                  uint64_t* __restrict__ bits) {
  uint32_t t = blockIdx.x * 256u + threadIdx.x;
  uint32_t w0 = t >> 6, lane = t & 63u;
  if (w0 >= (uint32_t)NWH) return;        // wave-uniform
  uint32_t w1 = w0 + (uint32_t)NWH;
  bool p0 = bin_pred(in, w0, lane);
  bool p1 = bin_pred(in, w1, lane);
  uint64_t m0 = __ballot(p0);
  uint64_t m1 = __ballot(p1);
  if (lane == 0) { bits[w0] = m0; bits[w1] = m1; }
}

// ------------- per-word neighborhood from LDS row triples -------------------
#define NB(dz,dy,dx) ((dx)==-1 ? Lb[(dz)+1][(dy)+1] : ((dx)==1 ? Rb[(dz)+1][(dy)+1] : Vv[(dz)+1][(dy)+1]))

// R16: two-phase gather -- ALL 27 row words loaded into explicit locals
// first (wide live range -> batched ds_reads, one lgkmcnt wait), then the
// per-word select/shift compute. Indices compile-time after unroll.
#define GATHER_W(SRC, lz, ly, w) \
  { \
    uint64_t Rr[9][3]; \
    _Pragma("unroll") \
    for (int q = 0; q < 9; ++q) { \
      int rb = LADDR((lz) + (q / 3) - 1, (ly) + (q % 3) - 1); \
      Rr[q][0] = SRC[rb]; Rr[q][1] = SRC[rb + 1]; Rr[q][2] = SRC[rb + 2]; \
    } \
    _Pragma("unroll") \
    for (int q = 0; q < 9; ++q) { \
      uint64_t r0 = Rr[q][0], r1 = Rr[q][1], r2 = Rr[q][2]; \
      uint64_t b = ((w) == 0) ? r0 : (((w) == 1) ? r1 : r2); \
      uint64_t a = ((w) == 0) ? 0ull : (((w) == 1) ? r0 : r1); \
      uint64_t d = ((w) == 0) ? r1 : (((w) == 1) ? r2 : 0ull); \
      Vv[q / 3][q % 3] = b; \
      Lb[q / 3][q % 3] = (b << 1) | (a >> 63); \
      Rb[q / 3][q % 3] = (b >> 1) | (d << 63); \
    } \
  }

// ---- balanced (OR, GE2) reduction: low serial depth for latency hiding ----
struct OG { uint64_t o, g; };
__device__ __forceinline__ OG og_leaf2(uint64_t a, uint64_t b) {
  OG r; r.o = a | b; r.g = a & b; return r;
}
__device__ __forceinline__ OG og_comb(OG a, OG b) {
  OG r; r.g = a.g | b.g | (a.o & b.o); r.o = a.o | b.o; return r;
}

// OG over the 18-neighborhood (faces+edges) and corners; both trees depth ~4.
#define OG_BUILD_18_C(og18, ogc) \
  OG a0 = og_leaf2(NB(-1,0,0), NB(1,0,0)); \
  OG a1 = og_leaf2(NB(0,-1,0), NB(0,1,0)); \
  OG a2 = og_leaf2(NB(0,0,-1), NB(0,0,1)); \
  OG e0 = og_leaf2(NB(-1,-1,0), NB(-1,1,0)); \
  OG e1 = og_leaf2(NB(-1,0,-1), NB(-1,0,1)); \
  OG e2 = og_leaf2(NB(1,-1,0),  NB(1,1,0)); \
  OG e3 = og_leaf2(NB(1,0,-1),  NB(1,0,1)); \
  OG e4 = og_leaf2(NB(0,-1,-1), NB(0,-1,1)); \
  OG e5 = og_leaf2(NB(0,1,-1),  NB(0,1,1)); \
  OG t0 = og_comb(a0, a1); \
  OG t1 = og_comb(a2, e0); \
  OG t2 = og_comb(e1, e2); \
  OG t3 = og_comb(e3, e4); \
  OG og18 = og_comb(og_comb(og_comb(t0, t1), og_comb(t2, t3)), e5); \
  OG c0 = og_leaf2(NB(-1,-1,-1), NB(-1,-1,1)); \
  OG c1 = og_leaf2(NB(-1,1,-1),  NB(-1,1,1)); \
  OG c2 = og_leaf2(NB(1,-1,-1),  NB(1,-1,1)); \
  OG c3 = og_leaf2(NB(1,1,-1),   NB(1,1,1)); \
  OG ogc = og_comb(og_comb(c0, c1), og_comb(c2, c3));

// ---------------------------- iteration kernel ------------------------------
// One block: 16x16 (z,y) core x full 192-bit x, halo 8 -> 32x32 LDS tile.
// ge2 on halo 7, then 8 subfield passes with shrinking halo; writes core only
// (or, final iteration, the float output directly from LDS).
__global__ __launch_bounds__(NTHREADS) void k_iter(const uint64_t* __restrict__ bin,
                                                   uint64_t* __restrict__ bout,
                                                   float4* __restrict__ outf,
                                                   int zero_pads) {
  __shared__ uint64_t Bt[TZ * PZ];
  __shared__ uint64_t Ge[TZ * PZ];
  const int tid = threadIdx.x;
  const int bid = blockIdx.x;
  const int n  = bid / 100;
  const int rm = bid - n * 100;
  const int tz = rm / 10, ty = rm - tz * 10;
  const int gz0 = 1 + 16 * tz, gy0 = 1 + 16 * ty;   // both odd

  // Zero bout's pad rows (z or y in {0,161}) once per replay (block 0, iter 1).
  if (zero_pads && bid == 0) {
    for (int j = tid; j < 1288; j += NTHREADS) {
      int nn, z, y;
      if (j < 648) { nn = j / 324; int r = j - nn * 324;
                     z = (r >= 162) ? 161 : 0; y = (r >= 162) ? r - 162 : r; }
      else { int j2 = j - 648; nn = j2 / 320; int r = j2 - nn * 320;
             y = (r >= 160) ? 161 : 0; z = 1 + ((r >= 160) ? r - 160 : r); }
      uint64_t* p = bout + (((nn * 162 + z) * 162) + y) * 3;
      p[0] = 0; p[1] = 0; p[2] = 0;
    }
  }

  // ---- load tile + halo 8 (w,ly fastest -> coalesced global reads) ----
  for (int ti = tid; ti < TZ * TY * 3; ti += NTHREADS) {
    int w = ti % 3, r = ti / 3, ly = r % TY, lz = r / TY;
    int z = gz0 - 8 + lz, y = gy0 - 8 + ly;
    uint64_t v = 0;
    if ((unsigned)z < 162u && (unsigned)y < 162u)
      v = bin[((n * 162 + z) * 162 + y) * 3 + w];
    Bt[LADDR(lz, ly) + w] = v;
  }
  __syncthreads();

  // ---- ge2 (C26>=2, not-endpoint) on halo 7 (30x30), tree reduction ----
  for (int ti = tid; ti < 30 * 30 * 3; ti += NTHREADS) {
    int w = ti % 3, r = ti / 3, iy = r % 30, iz = r / 30;
    int lz = 1 + iz, ly = 1 + iy;
    int base = LADDR(lz, ly) + w;
    uint64_t res = 0;
    if (Bt[base] != 0ull) {               // ge2 only consumed ANDed with center
      uint64_t Vv[3][3], Lb[3][3], Rb[3][3];
      GATHER_W(Bt, lz, ly, w)
      OG_BUILD_18_C(og18, ogc)
      res = og_comb(og18, ogc).g;         // GE2 over all 26
    }
    Ge[base] = res;
  }
  __syncthreads();

  // ---- 8 subfield passes, halo 7-k, parity per reference offsets order ----
  const int PLZ[8] = {1,0,1,0,1,0,1,0};   // lz parity (xo=0 -> z even -> lz odd)
  const int PLY[8] = {1,1,0,0,1,1,0,0};   // ly parity
#pragma unroll
  for (int k = 0; k < 8; ++k) {
    const int h = 7 - k, cnt1 = 8 + h;
    const uint64_t xmask = (k < 4) ? 0x5555555555555555ull : 0xAAAAAAAAAAAAAAAAull;
    const int s0 = 8 - h;
    const int slz = s0 + ((s0 ^ PLZ[k]) & 1);
    const int sly = s0 + ((s0 ^ PLY[k]) & 1);
    for (int ti = tid; ti < cnt1 * cnt1 * 3; ti += NTHREADS) {
      int w = ti % 3, r = ti / 3, iy = r % cnt1, iz = r / cnt1;
      int lz = slz + 2 * iz, ly = sly + 2 * iy;
      int base = LADDR(lz, ly) + w;
      uint64_t center = Bt[base];
      uint64_t act = center & xmask & Ge[base];
      if (act == 0ull) continue;
      uint64_t Vv[3][3], Lb[3][3], Rb[3][3];
      GATHER_W(Bt, lz, ly, w)

      // tree (OR,GE2) over 18-set and corners
      OG_BUILD_18_C(og18, ogc)
      OG og26 = og_comb(og18, ogc);
      uint64_t e18 = og18.o & ~og18.g;    // C18 == 1
      uint64_t e26 = og26.o & ~og26.g;    // C26 == 1

      // C6 via complemented faces: eq5 = exactly-1 missing, le4 = >=2 missing
      uint64_t m0f = ~NB(-1,0,0), m1f = ~NB(1,0,0), m2f = ~NB(0,-1,0);
      uint64_t m3f = ~NB(0,1,0),  m4f = ~NB(0,0,-1), m5f = ~NB(0,0,1);
      OG p0 = og_leaf2(m0f, m1f);
      OG p1 = og_leaf2(m2f, m3f);
      OG p2 = og_leaf2(m4f, m5f);
      OG pm = og_comb(og_comb(p0, p1), p2);
      uint64_t c6eq5 = pm.o & ~pm.g;
      uint64_t c6le4 = pm.g;

      uint64_t del = (c6eq5 | e26) & act;
      // B/A patterns only where a candidate isn't already decided
      uint64_t need = act & ~del & (e18 | c6le4);
      if (need != 0ull) {
        // B: corner set with its 6 octant face/edge cells all clear
        uint64_t badB = 0;
#pragma unroll
        for (int sz = -1; sz <= 1; sz += 2)
#pragma unroll
          for (int sy = -1; sy <= 1; sy += 2)
#pragma unroll
            for (int sx = -1; sx <= 1; sx += 2) {
              uint64_t oct = NB(sz,0,0) | NB(0,sy,0) | NB(0,0,sx)
                           | NB(sz,sy,0) | NB(sz,0,sx) | NB(0,sy,sx);
              badB |= NB(sz,sy,sx) & ~oct;
            }
        uint64_t b0ok = ~badB;

        // A: face clear with its full 4-cell in-plane ring set
        uint64_t badA = 0;
        badA |= ~NB(-1,0,0) & NB(-1,-1,0) & NB(-1,1,0) & NB(-1,0,-1) & NB(-1,0,1);
        badA |= ~NB( 1,0,0) & NB( 1,-1,0) & NB( 1,1,0) & NB( 1,0,-1) & NB( 1,0,1);
        badA |= ~NB(0,-1,0) & NB(-1,-1,0) & NB(1,-1,0) & NB(0,-1,-1) & NB(0,-1,1);
        badA |= ~NB(0, 1,0) & NB(-1, 1,0) & NB(1, 1,0) & NB(0, 1,-1) & NB(0, 1,1);
        badA |= ~NB(0,0,-1) & NB(-1,0,-1) & NB(1,0,-1) & NB(0,-1,-1) & NB(0,1,-1);
        badA |= ~NB(0,0, 1) & NB(-1,0, 1) & NB(1,0, 1) & NB(0,-1, 1) & NB(0,1, 1);
        uint64_t a0ok = ~badA;

        del |= ((e18 & b0ok) | (c6le4 & a0ok & b0ok)) & act;
      }
      if (del) Bt[base] = center & ~del;
      // readers only consume non-updated-parity bits; tearing-safe (R5 arg)
    }
    __syncthreads();
  }

  // ---- epilogue ----
  if (outf) {
    // final iteration: write float output for core directly from LDS
    for (int ti = tid; ti < CZ * CY * 40; ti += NTHREADS) {
      int g = ti % 40, r = ti / 40, iy = r % CY, iz = r / CY;
      int base = LADDR(8 + iz, 8 + iy);
      int bi = 1 + 4 * g;                 // padded x of first of 4 floats
      int wx = bi >> 6, sft = bi & 63;
      uint64_t v = Bt[base + wx] >> sft;
      if (sft > 60) v |= Bt[base + wx + 1] << (64 - sft);
      outf[((n * 160 + (gz0 + iz - 1)) * 160 + (gy0 + iy - 1)) * 40 + g] =
          make_float4((float)(v & 1u), (float)((v >> 1) & 1u),
                      (float)((v >> 2) & 1u), (float)((v >> 3) & 1u));
    }
  } else {
    // write core words back (disjoint across blocks)
    for (int ti = tid; ti < CZ * CY * 3; ti += NTHREADS) {
      int w = ti % 3, r = ti / 3, iy = r % CY, iz = r / CY;
      bout[((n * 162 + gz0 + iz) * 162 + (gy0 + iy)) * 3 + w] =
          Bt[LADDR(8 + iz, 8 + iy) + w];
    }
  }
}

// ---------------------------- launcher --------------------------------------
extern "C" void kernel_launch(void* const* d_in, const int* in_sizes, int n_in,
                              void* d_out, int out_size, void* d_ws, size_t ws_size,
                              hipStream_t stream) {
  const float* in = (const float*)d_in[0];
  float4* out = (float4*)d_out;
  uint64_t* A = (uint64_t*)d_ws;          // bitboard A
  uint64_t* B = A + NW;                   // bitboard B

  k_binarize<<<dim3((NWH * 64 + 255) / 256), dim3(256), 0, stream>>>(in, A);
  k_iter<<<dim3(200), dim3(NTHREADS), 0, stream>>>(A, B, nullptr, 1); // iter 1
  k_iter<<<dim3(200), dim3(NTHREADS), 0, stream>>>(B, A, nullptr, 0); // iter 2
  k_iter<<<dim3(200), dim3(NTHREADS), 0, stream>>>(A, B, nullptr, 0); // iter 3
  k_iter<<<dim3(200), dim3(NTHREADS), 0, stream>>>(B, A, nullptr, 0); // iter 4
  k_iter<<<dim3(200), dim3(NTHREADS), 0, stream>>>(A, nullptr, out, 0); // iter 5 -> out
}